// Round 14
// baseline (541.803 us; speedup 1.0000x reference)
//
#include <hip/hip_runtime.h>
#include <hip/hip_bf16.h>
#include <math.h>

typedef __hip_bfloat16 bf16;
typedef float f32x4 __attribute__((ext_vector_type(4)));
typedef __bf16 bf16x8 __attribute__((ext_vector_type(8)));

#define DEV __device__ __forceinline__

DEV float to_f(float v){ return v; }
DEV float to_f(bf16 v){ return __bfloat162float(v); }
DEV bf16 f2b(float v){ return __float2bfloat16(v); }
DEV unsigned short b2u(bf16 v){ return __builtin_bit_cast(unsigned short, v); }

DEV float gelu_f(float x){
  float z = 1.5957691216057308f*(x + 0.044715f*x*x*x);
  float e = __expf(-z);
  return x * __builtin_amdgcn_rcpf(1.0f + e);
}

DEV bf16x8 load_frag(const bf16* p, bool ok){
  uint4 u = make_uint4(0u,0u,0u,0u);
  if (ok) u = *(const uint4*)p;
  return __builtin_bit_cast(bf16x8, u);
}

DEV f32x4 mfma16(bf16x8 a, uint4 b, f32x4 c){
  return __builtin_amdgcn_mfma_f32_16x16x32_bf16(a, __builtin_bit_cast(bf16x8, b), c, 0, 0, 0);
}

DEV int swz8(int blk, int n){
  return (blk & 7) * (n >> 3) + (blk >> 3);
}

// async global->LDS DMA, 16 B per lane; lds dest wave-uniform base.
DEV void dma16(const void* g, void* l){
  __builtin_amdgcn_global_load_lds(
      (const __attribute__((address_space(1))) unsigned int*)g,
      (__attribute__((address_space(3))) unsigned int*)l,
      16, 0, 0);
}

#define NSLOT 64

// ---------------- encoder Conv_trio -------------------------------------------
// bf16 inputs with CIN%8==0 use vectorized uint4 channel loads (18 VMEM/thread
// instead of 144) — the round-13 profile showed the scalar path latency-bound.
template<typename TIN, int CIN, int COUT, int SUB, int STRIDE, int HI, int WI>
__global__ void trio_kernel(const TIN* __restrict__ in, const float* __restrict__ w,
                            const float* __restrict__ bias, bf16* __restrict__ out){
  constexpr int HO = HI/STRIDE, WO = WI/STRIDE;
  constexpr int CO_PER = COUT/SUB;
  int gtid = blockIdx.x*blockDim.x + threadIdx.x;
  int sub = gtid % SUB;
  int pix = gtid / SUB;
  int b = pix / (HO*WO); int rem = pix % (HO*WO);
  int y = rem / WO, x = rem % WO;

  float acc[CO_PER];
  #pragma unroll
  for (int j=0;j<CO_PER;j++) acc[j]=0.f;

  for (int ky=0;ky<3;ky++){
    int iy = (STRIDE==1) ? (y+ky-1) : (2*y+ky);
    if (iy<0 || iy>=HI) continue;
    for (int kx=0;kx<3;kx++){
      int ix = (STRIDE==1) ? (x+kx-1) : (2*x+kx);
      if (ix<0 || ix>=WI) continue;
      const TIN* ip = in + ((size_t)(b*HI+iy)*WI+ix)*CIN;
      const float* wp = w + ((ky*3+kx)*CIN)*COUT + sub*CO_PER;
      if constexpr (sizeof(TIN)==2 && (CIN%8)==0){
        #pragma unroll
        for (int v=0; v<CIN/8; v++){
          uint4 u = *(const uint4*)((const bf16*)ip + v*8);
          bf16x8 ch = __builtin_bit_cast(bf16x8, u);
          #pragma unroll
          for (int j=0;j<8;j++){
            float a = (float)ch[j];
            const float4* w4 = (const float4*)(wp + (size_t)(v*8+j)*COUT);
            #pragma unroll
            for (int q2=0;q2<CO_PER/4;q2++){
              float4 ww = w4[q2];
              acc[4*q2+0] += a*ww.x; acc[4*q2+1] += a*ww.y;
              acc[4*q2+2] += a*ww.z; acc[4*q2+3] += a*ww.w;
            }
          }
        }
      } else {
        #pragma unroll 4
        for (int ci=0; ci<CIN; ci++){
          float a = to_f(ip[ci]);
          const float4* w4 = (const float4*)(wp + (size_t)ci*COUT);
          #pragma unroll
          for (int j=0;j<CO_PER/4;j++){
            float4 ww = w4[j];
            acc[4*j+0] += a*ww.x; acc[4*j+1] += a*ww.y;
            acc[4*j+2] += a*ww.z; acc[4*j+3] += a*ww.w;
          }
        }
      }
    }
  }

  float s1=0.f, s2=0.f;
  #pragma unroll
  for (int j=0;j<CO_PER;j++){
    acc[j] += bias[sub*CO_PER+j];
    s1 += acc[j]; s2 += acc[j]*acc[j];
  }
  if (SUB>=2){ s1 += __shfl_xor(s1,1,64); s2 += __shfl_xor(s2,1,64); }
  if (SUB>=4){ s1 += __shfl_xor(s1,2,64); s2 += __shfl_xor(s2,2,64); }
  float mu  = s1*(1.0f/COUT);
  float var = s2*(1.0f/COUT) - mu*mu;
  float sc  = rsqrtf(var + 1e-6f);

  bf16* op = out + (size_t)pix*COUT + sub*CO_PER;
  #pragma unroll
  for (int j=0;j<CO_PER;j++) op[j] = f2b(gelu_f((acc[j]-mu)*sc));
}

// ---------------- weight repack -----------------------------------------------
__global__ void repack_up(const float* __restrict__ w, bf16* __restrict__ bp){
  int v = blockIdx.x*256 + threadIdx.x;
  if (v >= 9*2*4*64*8) return;
  int j = v & 7; int lane = (v>>3)&63; int nt = (v>>9)&3; int c = (v>>11)&1; int tap = v>>12;
  int ci = c*32 + (lane>>4)*8 + j;
  int co = (lane&15)*4 + nt;
  bp[v] = f2b(w[(tap*64+ci)*64 + co]);
}

__global__ void repack_mask(const float* __restrict__ w, bf16* __restrict__ bp){
  int v = blockIdx.x*256 + threadIdx.x;
  if (v >= 9*2*64*8) return;
  int j = v & 7; int lane = (v>>3)&63; int c = (v>>9)&1; int tap = v>>10;
  int ci = c*32 + (lane>>4)*8 + j;
  int n = lane & 15;
  bp[v] = (n < 4) ? f2b(w[(tap*64+ci)*4 + n]) : f2b(0.0f);
}

// ------------- conv_transpose, stride-2 along y (DIM=0) -----------------------
template<int HI, int WI>
__global__ void upconv_dim0(const bf16* __restrict__ in, const bf16* __restrict__ bpack,
                            const float* __restrict__ upb, bf16* __restrict__ out){
  constexpr int HO = 2*HI, WO = WI, XT = WI/32;
  int lane = threadIdx.x & 63, wv = threadIdx.x >> 6;
  int wtile = swz8(blockIdx.x, gridDim.x)*4 + wv;
  int m = lane & 15, quad = lane >> 4;

  int x0 = (wtile % XT)*32;
  int o  = (wtile / XT) % HO;
  int b  = wtile / (XT*HO);

  int q = o >> 1;
  int stk[2], stq[2]; int nst;
  if (o & 1){ stk[0]=1; stq[0]=q; nst=1; }
  else {
    nst = 0;
    if (q >= 1){ stk[0]=0; stq[0]=q-1; nst=1; }
    stk[nst]=2; stq[nst]=q; nst++;
  }

  f32x4 acc[2][4];
  #pragma unroll
  for (int t=0;t<2;t++)
    #pragma unroll
    for (int nt=0;nt<4;nt++) acc[t][nt] = (f32x4){0.f,0.f,0.f,0.f};

  const uint4* bp4 = (const uint4*)bpack;

  #pragma unroll 1
  for (int s=0; s<nst; s++){
    int kyt = stk[s];
    const bf16* rowp = in + ((size_t)(b*HI+stq[s])*WI)*64 + quad*8;
    #pragma unroll
    for (int ut=0; ut<3; ut++){
      #pragma unroll
      for (int c=0;c<2;c++){
        #pragma unroll
        for (int t=0;t<2;t++){
          int ix = x0 + t*16 + m - 1 + ut;
          bf16x8 a = load_frag(rowp + (size_t)ix*64 + c*32, ix>=0 && ix<WI);
          #pragma unroll
          for (int nt=0;nt<4;nt++){
            uint4 Bq = bp4[(((kyt*3+ut)*2+c)*4+nt)*64 + lane];
            acc[t][nt] = mfma16(a, Bq, acc[t][nt]);
          }
        }
      }
    }
  }

  float4 bv = *(const float4*)(upb + m*4);
  size_t rowbase = ((size_t)b*HO + o)*WO;
  #pragma unroll
  for (int t=0;t<2;t++){
    #pragma unroll
    for (int r=0;r<4;r++){
      int p = x0 + t*16 + quad*4 + r;
      float g0 = gelu_f(acc[t][0][r] + bv.x);
      float g1 = gelu_f(acc[t][1][r] + bv.y);
      float g2 = gelu_f(acc[t][2][r] + bv.z);
      float g3 = gelu_f(acc[t][3][r] + bv.w);
      unsigned int lo = (unsigned int)b2u(f2b(g0)) | ((unsigned int)b2u(f2b(g1))<<16);
      unsigned int hi = (unsigned int)b2u(f2b(g2)) | ((unsigned int)b2u(f2b(g3))<<16);
      *(uint2*)(out + (rowbase + p)*64 + m*4) = make_uint2(lo,hi);
    }
  }
}

// ------------- conv_transpose, stride-2 along x (DIM=1) -----------------------
template<int HI, int WI>
__global__ void upconv_dim1(const bf16* __restrict__ in, const bf16* __restrict__ bpack,
                            const float* __restrict__ upb, bf16* __restrict__ out){
  constexpr int HO = HI, WO = 2*WI, QT = WI/16;
  int lane = threadIdx.x & 63, wv = threadIdx.x >> 6;
  int wtile = swz8(blockIdx.x, gridDim.x)*4 + wv;
  int m = lane & 15, quad = lane >> 4;

  int q0 = (wtile % QT)*16;
  int y  = (wtile / QT) % HI;
  int b  = wtile / (QT*HI);

  f32x4 ae[4], ao[4];
  #pragma unroll
  for (int nt=0;nt<4;nt++){ ae[nt]=(f32x4){0.f,0.f,0.f,0.f}; ao[nt]=(f32x4){0.f,0.f,0.f,0.f}; }

  const uint4* bp4 = (const uint4*)bpack;

  #pragma unroll 1
  for (int ky=0; ky<3; ky++){
    int iy = y + ky - 1;
    if (iy < 0 || iy >= HI) continue;
    const bf16* rowp = in + ((size_t)(b*HI+iy)*WI)*64 + quad*8;
    #pragma unroll
    for (int c=0;c<2;c++){
      int qa = q0 + m;
      bf16x8 Au = load_frag(rowp + (size_t)qa*64 + c*32, true);
      bf16x8 As = load_frag(rowp + (size_t)(qa-1)*64 + c*32, qa >= 1);
      #pragma unroll
      for (int nt=0;nt<4;nt++){
        uint4 B0 = bp4[(((ky*3+0)*2+c)*4+nt)*64 + lane];
        uint4 B1 = bp4[(((ky*3+1)*2+c)*4+nt)*64 + lane];
        uint4 B2 = bp4[(((ky*3+2)*2+c)*4+nt)*64 + lane];
        ae[nt] = mfma16(As, B0, ae[nt]);
        ae[nt] = mfma16(Au, B2, ae[nt]);
        ao[nt] = mfma16(Au, B1, ao[nt]);
      }
    }
  }

  float4 bv = *(const float4*)(upb + m*4);
  size_t rowbase = ((size_t)b*HO + y)*WO;
  #pragma unroll
  for (int r=0;r<4;r++){
    int qq = q0 + quad*4 + r;
    {
      float g0 = gelu_f(ae[0][r] + bv.x);
      float g1 = gelu_f(ae[1][r] + bv.y);
      float g2 = gelu_f(ae[2][r] + bv.z);
      float g3 = gelu_f(ae[3][r] + bv.w);
      unsigned int lo = (unsigned int)b2u(f2b(g0)) | ((unsigned int)b2u(f2b(g1))<<16);
      unsigned int hi = (unsigned int)b2u(f2b(g2)) | ((unsigned int)b2u(f2b(g3))<<16);
      *(uint2*)(out + (rowbase + 2*qq)*64 + m*4) = make_uint2(lo,hi);
    }
    {
      float g0 = gelu_f(ao[0][r] + bv.x);
      float g1 = gelu_f(ao[1][r] + bv.y);
      float g2 = gelu_f(ao[2][r] + bv.z);
      float g3 = gelu_f(ao[3][r] + bv.w);
      unsigned int lo = (unsigned int)b2u(f2b(g0)) | ((unsigned int)b2u(f2b(g1))<<16);
      unsigned int hi = (unsigned int)b2u(f2b(g2)) | ((unsigned int)b2u(f2b(g3))<<16);
      *(uint2*)(out + (rowbase + 2*qq+1)*64 + m*4) = make_uint2(lo,hi);
    }
  }
}

// ---------------- maskloss, register form — step 0 only ------------------------
template<int STEP, int DIM, int HH, int WW, int TILES>
__global__ void maskloss_mfma(const bf16* __restrict__ feat, const bf16* __restrict__ mpack,
                              const float* __restrict__ mb, const float* __restrict__ img,
                              const float* __restrict__ masks_in, float* __restrict__ masks_out,
                              float* __restrict__ accbuf){
  __shared__ float llog[4][64][4];
  __shared__ float red[4][2];
  int lane = threadIdx.x & 63;
  int wv   = threadIdx.x >> 6;
  int wtile = swz8(blockIdx.x, gridDim.x)*4 + wv;
  int m = lane & 15, quad = lane >> 4;

  constexpr int TPR = WW/(16*TILES);
  int x0 = (wtile % TPR)*(16*TILES);
  int y  = (wtile / TPR) % HH;
  int b  = wtile / (TPR*HH);

  const uint4* bp4 = (const uint4*)mpack;

  #pragma unroll 1
  for (int t=0; t<TILES; t++){
    f32x4 acc4 = (f32x4){0.f,0.f,0.f,0.f};
    #pragma unroll
    for (int c=0;c<2;c++){
      bf16x8 afr[9];
      #pragma unroll
      for (int ky=0; ky<3; ky++){
        int iy = y + ky - 1;
        bool rowok = (iy >= 0) && (iy < HH);
        const bf16* rowp = feat + ((size_t)(b*HH+iy)*WW)*64 + quad*8 + c*32;
        #pragma unroll
        for (int kx=0; kx<3; kx++){
          int ix = x0 + t*16 + m + kx - 1;
          bool ok = rowok && (ix >= 0) && (ix < WW);
          afr[ky*3+kx] = load_frag(rowp + (size_t)ix*64, ok);
        }
      }
      #pragma unroll
      for (int tap=0; tap<9; tap++){
        uint4 bb = bp4[(tap*2+c)*64 + lane];
        acc4 = mfma16(afr[tap], bb, acc4);
      }
    }
    if (m < 4){
      #pragma unroll
      for (int r=0;r<4;r++) llog[wv][t*16 + quad*4 + r][m] = acc4[r] + mb[m];
    }
  }
  __syncthreads();

  float ent = 0.f, mse = 0.f;
  if (lane < 16*TILES){
    int p = lane; int xx = x0 + p;
    float l0 = llog[wv][p][0], l1 = llog[wv][p][1];
    float l2 = llog[wv][p][2], l3 = llog[wv][p][3];
    float mx = fmaxf(fmaxf(l0,l1), fmaxf(l2,l3));
    float e0=__expf(l0-mx), e1=__expf(l1-mx), e2=__expf(l2-mx), e3=__expf(l3-mx);
    float inv = __builtin_amdgcn_rcpf(e0+e1+e2+e3);
    float p0=e0*inv, p1=e1*inv, p2=e2*inv, p3=e3*inv;
    float sval = p1 + 2.f*p2 + 3.f*p3;

    constexpr int HM = (DIM==0)? HH/2 : HH;
    constexpr int WM = (DIM==0)? WW : WW/2;
    int my = (DIM==0)? (y>>1) : y;
    int mxi = (DIM==1)? (xx>>1) : xx;
    float mv = masks_in[((size_t)b*HM + my)*WM + mxi];
    masks_out[((size_t)b*HH + y)*WW + xx] = mv + 0.25f*sval;

    ent = -(p0*__logf(p0+1e-8f) + p1*__logf(p1+1e-8f) +
            p2*__logf(p2+1e-8f) + p3*__logf(p3+1e-8f));

    constexpr int FH = 256/HH, FW = 256/WW;
    float isum = 0.f;
    const float* ib = img + ((size_t)b*256 + y*FH)*256 + xx*FW;
    #pragma unroll
    for (int dy=0; dy<FH; dy++)
      #pragma unroll
      for (int dx=0; dx<FW; dx++) isum += ib[dy*256+dx];
    float img_ds = isum * (1.0f/(FH*FW));
    float d = sval*(1.0f/3.0f) - img_ds;
    mse = d*d;
  }

  #pragma unroll
  for (int off=1; off<64; off<<=1){
    ent += __shfl_xor(ent, off, 64);
    mse += __shfl_xor(mse, off, 64);
  }
  if (lane == 0){ red[wv][0] = ent; red[wv][1] = mse; }
  __syncthreads();
  if (threadIdx.x == 0){
    float e  = red[0][0] + red[1][0] + red[2][0] + red[3][0];
    float ms = red[0][1] + red[1][1] + red[2][1] + red[3][1];
    int slot = blockIdx.x & (NSLOT-1);
    atomicAdd(accbuf + (2*STEP  )*NSLOT + slot, e);
    atomicAdd(accbuf + (2*STEP+1)*NSLOT + slot, ms);
  }
}

// ---------------- maskloss via async LDS staging (WW >= 64) --------------------
template<int STEP, int DIM, int HH, int WW>
__global__ void maskloss_lds(const bf16* __restrict__ feat, const bf16* __restrict__ mpack,
                             const float* __restrict__ mb, const float* __restrict__ img,
                             const float* __restrict__ masks_in, float* __restrict__ masks_out,
                             float* __restrict__ accbuf){
  constexpr int NBrow = WW/64;
  constexpr int PITCH = 9216;                // 72 px * 128 B
  __shared__ __align__(16) char smem[3*PITCH];
  __shared__ float llog[4][16][4];
  __shared__ float red[4][2];
  int tid = threadIdx.x;
  int lane = tid & 63, wv = tid >> 6;
  int bi = swz8(blockIdx.x, gridDim.x);
  int x0 = (bi % NBrow)*64;
  int y  = (bi / NBrow) % HH;
  int b  = bi / (NBrow*HH);
  int m = lane & 15, quad = lane >> 4;

  bool rok[3];
  #pragma unroll
  for (int r=0;r<3;r++){ int iy=y+r-1; rok[r] = (iy>=0)&&(iy<HH); }

  for (int k = wv; k < 27; k += 4){
    int r = k/9, coff = (k%9)*1024;
    if (!rok[r]) continue;
    int iy = y + r - 1;
    const char* g = (const char*)(feat + ((size_t)(b*HH+iy)*WW + x0 - 1)*64)
                    + coff + lane*16;
    dma16(g, smem + r*PITCH + coff);
  }
  asm volatile("s_waitcnt vmcnt(0)" ::: "memory");
  __syncthreads();
  if (x0 == 0 && tid < 96)
    ((float*)(smem + (tid>>5)*PITCH))[tid & 31] = 0.f;
  if (x0 + 64 == WW && tid >= 128 && tid < 224){
    int t = tid - 128;
    ((float*)(smem + (t>>5)*PITCH + 65*128))[t & 31] = 0.f;
  }
  __syncthreads();

  const uint4* bp4 = (const uint4*)mpack;
  f32x4 accA = (f32x4){0.f,0.f,0.f,0.f};
  f32x4 accB = (f32x4){0.f,0.f,0.f,0.f};
  #pragma unroll 1
  for (int ky=0; ky<3; ky++){
    if (!rok[ky]) continue;
    const char* rowl = smem + ky*PITCH;
    #pragma unroll
    for (int kx=0; kx<3; kx++){
      int lp = wv*16 + m + kx;
      const char* pl = rowl + lp*128 + quad*16;
      bf16x8 a0 = __builtin_bit_cast(bf16x8, *(const uint4*)(pl));
      bf16x8 a1 = __builtin_bit_cast(bf16x8, *(const uint4*)(pl + 64));
      uint4 b0 = bp4[((ky*3+kx)*2+0)*64 + lane];
      uint4 b1 = bp4[((ky*3+kx)*2+1)*64 + lane];
      accA = mfma16(a0, b0, accA);
      accB = mfma16(a1, b1, accB);
    }
  }

  if (m < 4){
    #pragma unroll
    for (int r=0;r<4;r++) llog[wv][quad*4+r][m] = accA[r] + accB[r] + mb[m];
  }
  __syncthreads();

  float ent = 0.f, mse = 0.f;
  if (lane < 16){
    int p = lane; int xx = x0 + wv*16 + p;
    float l0 = llog[wv][p][0], l1 = llog[wv][p][1];
    float l2 = llog[wv][p][2], l3 = llog[wv][p][3];
    float mx = fmaxf(fmaxf(l0,l1), fmaxf(l2,l3));
    float e0=__expf(l0-mx), e1=__expf(l1-mx), e2=__expf(l2-mx), e3=__expf(l3-mx);
    float inv = __builtin_amdgcn_rcpf(e0+e1+e2+e3);
    float p0=e0*inv, p1=e1*inv, p2=e2*inv, p3=e3*inv;
    float sval = p1 + 2.f*p2 + 3.f*p3;

    constexpr int HM = (DIM==0)? HH/2 : HH;
    constexpr int WM = (DIM==0)? WW : WW/2;
    int my = (DIM==0)? (y>>1) : y;
    int mxi = (DIM==1)? (xx>>1) : xx;
    float mv = masks_in[((size_t)b*HM + my)*WM + mxi];
    masks_out[((size_t)b*HH + y)*WW + xx] = mv + 0.25f*sval;

    ent = -(p0*__logf(p0+1e-8f) + p1*__logf(p1+1e-8f) +
            p2*__logf(p2+1e-8f) + p3*__logf(p3+1e-8f));

    constexpr int FH = 256/HH, FW = 256/WW;
    float isum = 0.f;
    const float* ib = img + ((size_t)b*256 + y*FH)*256 + xx*FW;
    #pragma unroll
    for (int dy=0; dy<FH; dy++)
      #pragma unroll
      for (int dx=0; dx<FW; dx++) isum += ib[dy*256+dx];
    float img_ds = isum * (1.0f/(FH*FW));
    float d = sval*(1.0f/3.0f) - img_ds;
    mse = d*d;
  }

  #pragma unroll
  for (int off=1; off<64; off<<=1){
    ent += __shfl_xor(ent, off, 64);
    mse += __shfl_xor(mse, off, 64);
  }
  if (lane == 0){ red[wv][0] = ent; red[wv][1] = mse; }
  __syncthreads();
  if (threadIdx.x == 0){
    float e  = red[0][0] + red[1][0] + red[2][0] + red[3][0];
    float ms = red[0][1] + red[1][1] + red[2][1] + red[3][1];
    int slot = blockIdx.x & (NSLOT-1);
    atomicAdd(accbuf + (2*STEP  )*NSLOT + slot, e);
    atomicAdd(accbuf + (2*STEP+1)*NSLOT + slot, ms);
  }
}

__global__ void finalize_kernel(const float* __restrict__ acc, float* __restrict__ out){
  int lane = threadIdx.x & 63;
  float v[12];
  #pragma unroll
  for (int i=0;i<12;i++){
    float x = acc[i*NSLOT + lane];
    #pragma unroll
    for (int off=1; off<64; off<<=1) x += __shfl_xor(x, off, 64);
    v[i] = x;
  }
  if (lane == 0){
    const float lw[6] = {0.1f,0.1f,0.5f,0.5f,1.0f,1.0f};
    const float nn[6] = {16384.f,32768.f,65536.f,131072.f,262144.f,524288.f};
    float L=0.f;
    for (int i=0;i<6;i++) L += lw[i]*((v[2*i] + v[2*i+1])/nn[i]);
    out[0]=L;
  }
}

extern "C" void kernel_launch(void* const* d_in, const int* in_sizes, int n_in,
                              void* d_out, int out_size, void* d_ws, size_t ws_size,
                              hipStream_t stream){
  const float* image  = (const float*)d_in[0];
  const float* w1=(const float*)d_in[2];  const float* b1=(const float*)d_in[3];
  const float* w2=(const float*)d_in[4];  const float* b2=(const float*)d_in[5];
  const float* w3=(const float*)d_in[6];  const float* b3=(const float*)d_in[7];
  const float* w4=(const float*)d_in[8];  const float* b4=(const float*)d_in[9];
  const float* upw=(const float*)d_in[10];const float* upb=(const float*)d_in[11];
  const float* mw=(const float*)d_in[12]; const float* mb=(const float*)d_in[13];
  const float* masks0=(const float*)d_in[14];
  float* out = (float*)d_out;

  char* ws = (char*)d_ws;
  size_t off = 0;
  auto alloc = [&](size_t bytes)->char*{
    char* p = ws + off; off += (bytes + 255) & ~(size_t)255; return p;
  };
  bf16* enc1  = (bf16*)alloc((size_t)8*256*256*16*2);
  bf16* enc2  = (bf16*)alloc((size_t)8*128*128*16*2);
  bf16* enc3  = (bf16*)alloc((size_t)8*64*64*32*2);
  bf16* featA = (bf16*)alloc((size_t)8*256*256*64*2);
  bf16* featB = (bf16*)alloc((size_t)8*256*128*64*2);
  float* mbA  = (float*)alloc((size_t)8*256*128*4);
  float* mbB  = (float*)alloc((size_t)8*128*128*4);
  bf16* packU = (bf16*)alloc((size_t)9*2*4*64*8*2);
  bf16* packM = (bf16*)alloc((size_t)9*2*64*8*2);
  float* acc  = (float*)alloc(12*NSLOT*sizeof(float));

  hipMemsetAsync(acc, 0, 12*NSLOT*sizeof(float), stream);

  repack_up  <<<144,256,0,stream>>>(upw, packU);
  repack_mask<<< 36,256,0,stream>>>(mw,  packM);

  // encoder
  trio_kernel<float,1,16,1,1,256,256><<<8*256*256/256,256,0,stream>>>(image,w1,b1,enc1);
  trio_kernel<bf16,16,16,1,2,256,256><<<8*128*128/256,256,0,stream>>>(enc1,w2,b2,enc2);
  trio_kernel<bf16,16,32,2,2,128,128><<<8*64*64*2/256,256,0,stream>>>(enc2,w3,b3,enc3);
  trio_kernel<bf16,32,64,4,2,64,64><<<8*32*32*4/256,256,0,stream>>>(enc3,w4,b4,featA);

  // step 0: (32,32) -> (64,32)
  upconv_dim0<32,32><<<128,256,0,stream>>>(featA,packU,upb,featB);
  maskloss_mfma<0,0,64,32,2><<<128,256,0,stream>>>(featB,packM,mb,image,masks0,mbA,acc);
  // step 1: (64,32) -> (64,64)
  upconv_dim1<64,32><<<256,256,0,stream>>>(featB,packU,upb,featA);
  maskloss_lds<1,1,64,64><<<512,256,0,stream>>>(featA,packM,mb,image,mbA,mbB,acc);
  // step 2: (64,64) -> (128,64)
  upconv_dim0<64,64><<<512,256,0,stream>>>(featA,packU,upb,featB);
  maskloss_lds<2,0,128,64><<<1024,256,0,stream>>>(featB,packM,mb,image,mbB,mbA,acc);
  // step 3: (128,64) -> (128,128)
  upconv_dim1<128,64><<<1024,256,0,stream>>>(featB,packU,upb,featA);
  maskloss_lds<3,1,128,128><<<2048,256,0,stream>>>(featA,packM,mb,image,mbA,mbB,acc);
  // step 4: (128,128) -> (256,128)
  upconv_dim0<128,128><<<2048,256,0,stream>>>(featA,packU,upb,featB);
  maskloss_lds<4,0,256,128><<<4096,256,0,stream>>>(featB,packM,mb,image,mbB,mbA,acc);
  // step 5: (256,128) -> (256,256)
  upconv_dim1<256,128><<<4096,256,0,stream>>>(featB,packU,upb,featA);
  maskloss_lds<5,1,256,256><<<8192,256,0,stream>>>(featA,packM,mb,image,mbA,out+1,acc);

  finalize_kernel<<<1,64,0,stream>>>(acc,out);
}

// Round 15
// 474.466 us; speedup vs baseline: 1.1419x; 1.1419x over previous
//
#include <hip/hip_runtime.h>
#include <hip/hip_bf16.h>
#include <math.h>

typedef __hip_bfloat16 bf16;
typedef float f32x4 __attribute__((ext_vector_type(4)));
typedef __bf16 bf16x8 __attribute__((ext_vector_type(8)));

#define DEV __device__ __forceinline__

DEV float to_f(float v){ return v; }
DEV float to_f(bf16 v){ return __bfloat162float(v); }
DEV bf16 f2b(float v){ return __float2bfloat16(v); }
DEV unsigned short b2u(bf16 v){ return __builtin_bit_cast(unsigned short, v); }

DEV float gelu_f(float x){
  float z = 1.5957691216057308f*(x + 0.044715f*x*x*x);
  float e = __expf(-z);
  return x * __builtin_amdgcn_rcpf(1.0f + e);
}

DEV bf16x8 load_frag(const bf16* p, bool ok){
  uint4 u = make_uint4(0u,0u,0u,0u);
  if (ok) u = *(const uint4*)p;
  return __builtin_bit_cast(bf16x8, u);
}

DEV f32x4 mfma16(bf16x8 a, uint4 b, f32x4 c){
  return __builtin_amdgcn_mfma_f32_16x16x32_bf16(a, __builtin_bit_cast(bf16x8, b), c, 0, 0, 0);
}

DEV int swz8(int blk, int n){
  return (blk & 7) * (n >> 3) + (blk >> 3);
}

// async global->LDS DMA, 16 B per lane; lds dest wave-uniform base.
DEV void dma16(const void* g, void* l){
  __builtin_amdgcn_global_load_lds(
      (const __attribute__((address_space(1))) unsigned int*)g,
      (__attribute__((address_space(3))) unsigned int*)l,
      16, 0, 0);
}

#define NSLOT 64

// ---------------- encoder Conv_trio -------------------------------------------
// SUB lanes share one pixel's COUT channels. Round-14 profile: trio4 was
// grid-starved (128 blocks, 4608 FMA/thread) -> SUB bumped so every trio has
// >=512 blocks and <=1.2k FMA/thread. Channel-norm via generalized shfl_xor.
template<typename TIN, int CIN, int COUT, int SUB, int STRIDE, int HI, int WI>
__global__ void trio_kernel(const TIN* __restrict__ in, const float* __restrict__ w,
                            const float* __restrict__ bias, bf16* __restrict__ out){
  constexpr int HO = HI/STRIDE, WO = WI/STRIDE;
  constexpr int CO_PER = COUT/SUB;
  int gtid = blockIdx.x*blockDim.x + threadIdx.x;
  int sub = gtid % SUB;
  int pix = gtid / SUB;
  int b = pix / (HO*WO); int rem = pix % (HO*WO);
  int y = rem / WO, x = rem % WO;

  float acc[CO_PER];
  #pragma unroll
  for (int j=0;j<CO_PER;j++) acc[j]=0.f;

  for (int ky=0;ky<3;ky++){
    int iy = (STRIDE==1) ? (y+ky-1) : (2*y+ky);
    if (iy<0 || iy>=HI) continue;
    for (int kx=0;kx<3;kx++){
      int ix = (STRIDE==1) ? (x+kx-1) : (2*x+kx);
      if (ix<0 || ix>=WI) continue;
      const TIN* ip = in + ((size_t)(b*HI+iy)*WI+ix)*CIN;
      const float* wp = w + ((ky*3+kx)*CIN)*COUT + sub*CO_PER;
      if constexpr (sizeof(TIN)==2 && (CIN%8)==0){
        #pragma unroll
        for (int v=0; v<CIN/8; v++){
          uint4 u = *(const uint4*)((const bf16*)ip + v*8);
          bf16x8 ch = __builtin_bit_cast(bf16x8, u);
          #pragma unroll
          for (int j=0;j<8;j++){
            float a = (float)ch[j];
            const float4* w4 = (const float4*)(wp + (size_t)(v*8+j)*COUT);
            #pragma unroll
            for (int q2=0;q2<CO_PER/4;q2++){
              float4 ww = w4[q2];
              acc[4*q2+0] += a*ww.x; acc[4*q2+1] += a*ww.y;
              acc[4*q2+2] += a*ww.z; acc[4*q2+3] += a*ww.w;
            }
          }
        }
      } else {
        #pragma unroll 4
        for (int ci=0; ci<CIN; ci++){
          float a = to_f(ip[ci]);
          const float4* w4 = (const float4*)(wp + (size_t)ci*COUT);
          #pragma unroll
          for (int j=0;j<CO_PER/4;j++){
            float4 ww = w4[j];
            acc[4*j+0] += a*ww.x; acc[4*j+1] += a*ww.y;
            acc[4*j+2] += a*ww.z; acc[4*j+3] += a*ww.w;
          }
        }
      }
    }
  }

  float s1=0.f, s2=0.f;
  #pragma unroll
  for (int j=0;j<CO_PER;j++){
    acc[j] += bias[sub*CO_PER+j];
    s1 += acc[j]; s2 += acc[j]*acc[j];
  }
  #pragma unroll
  for (int off=1; off<SUB; off<<=1){
    s1 += __shfl_xor(s1,off,64);
    s2 += __shfl_xor(s2,off,64);
  }
  float mu  = s1*(1.0f/COUT);
  float var = s2*(1.0f/COUT) - mu*mu;
  float sc  = rsqrtf(var + 1e-6f);

  bf16* op = out + (size_t)pix*COUT + sub*CO_PER;
  #pragma unroll
  for (int j=0;j<CO_PER;j++) op[j] = f2b(gelu_f((acc[j]-mu)*sc));
}

// ---------------- weight repack -----------------------------------------------
__global__ void repack_up(const float* __restrict__ w, bf16* __restrict__ bp){
  int v = blockIdx.x*256 + threadIdx.x;
  if (v >= 9*2*4*64*8) return;
  int j = v & 7; int lane = (v>>3)&63; int nt = (v>>9)&3; int c = (v>>11)&1; int tap = v>>12;
  int ci = c*32 + (lane>>4)*8 + j;
  int co = (lane&15)*4 + nt;
  bp[v] = f2b(w[(tap*64+ci)*64 + co]);
}

__global__ void repack_mask(const float* __restrict__ w, bf16* __restrict__ bp){
  int v = blockIdx.x*256 + threadIdx.x;
  if (v >= 9*2*64*8) return;
  int j = v & 7; int lane = (v>>3)&63; int c = (v>>9)&1; int tap = v>>10;
  int ci = c*32 + (lane>>4)*8 + j;
  int n = lane & 15;
  bp[v] = (n < 4) ? f2b(w[(tap*64+ci)*4 + n]) : f2b(0.0f);
}

// ------------- conv_transpose, stride-2 along y (DIM=0) -----------------------
template<int HI, int WI>
__global__ void upconv_dim0(const bf16* __restrict__ in, const bf16* __restrict__ bpack,
                            const float* __restrict__ upb, bf16* __restrict__ out){
  constexpr int HO = 2*HI, WO = WI, XT = WI/32;
  int lane = threadIdx.x & 63, wv = threadIdx.x >> 6;
  int wtile = swz8(blockIdx.x, gridDim.x)*4 + wv;
  int m = lane & 15, quad = lane >> 4;

  int x0 = (wtile % XT)*32;
  int o  = (wtile / XT) % HO;
  int b  = wtile / (XT*HO);

  int q = o >> 1;
  int stk[2], stq[2]; int nst;
  if (o & 1){ stk[0]=1; stq[0]=q; nst=1; }
  else {
    nst = 0;
    if (q >= 1){ stk[0]=0; stq[0]=q-1; nst=1; }
    stk[nst]=2; stq[nst]=q; nst++;
  }

  f32x4 acc[2][4];
  #pragma unroll
  for (int t=0;t<2;t++)
    #pragma unroll
    for (int nt=0;nt<4;nt++) acc[t][nt] = (f32x4){0.f,0.f,0.f,0.f};

  const uint4* bp4 = (const uint4*)bpack;

  #pragma unroll 1
  for (int s=0; s<nst; s++){
    int kyt = stk[s];
    const bf16* rowp = in + ((size_t)(b*HI+stq[s])*WI)*64 + quad*8;
    #pragma unroll
    for (int ut=0; ut<3; ut++){
      #pragma unroll
      for (int c=0;c<2;c++){
        #pragma unroll
        for (int t=0;t<2;t++){
          int ix = x0 + t*16 + m - 1 + ut;
          bf16x8 a = load_frag(rowp + (size_t)ix*64 + c*32, ix>=0 && ix<WI);
          #pragma unroll
          for (int nt=0;nt<4;nt++){
            uint4 Bq = bp4[(((kyt*3+ut)*2+c)*4+nt)*64 + lane];
            acc[t][nt] = mfma16(a, Bq, acc[t][nt]);
          }
        }
      }
    }
  }

  float4 bv = *(const float4*)(upb + m*4);
  size_t rowbase = ((size_t)b*HO + o)*WO;
  #pragma unroll
  for (int t=0;t<2;t++){
    #pragma unroll
    for (int r=0;r<4;r++){
      int p = x0 + t*16 + quad*4 + r;
      float g0 = gelu_f(acc[t][0][r] + bv.x);
      float g1 = gelu_f(acc[t][1][r] + bv.y);
      float g2 = gelu_f(acc[t][2][r] + bv.z);
      float g3 = gelu_f(acc[t][3][r] + bv.w);
      unsigned int lo = (unsigned int)b2u(f2b(g0)) | ((unsigned int)b2u(f2b(g1))<<16);
      unsigned int hi = (unsigned int)b2u(f2b(g2)) | ((unsigned int)b2u(f2b(g3))<<16);
      *(uint2*)(out + (rowbase + p)*64 + m*4) = make_uint2(lo,hi);
    }
  }
}

// ------------- conv_transpose, stride-2 along x (DIM=1) -----------------------
template<int HI, int WI>
__global__ void upconv_dim1(const bf16* __restrict__ in, const bf16* __restrict__ bpack,
                            const float* __restrict__ upb, bf16* __restrict__ out){
  constexpr int HO = HI, WO = 2*WI, QT = WI/16;
  int lane = threadIdx.x & 63, wv = threadIdx.x >> 6;
  int wtile = swz8(blockIdx.x, gridDim.x)*4 + wv;
  int m = lane & 15, quad = lane >> 4;

  int q0 = (wtile % QT)*16;
  int y  = (wtile / QT) % HI;
  int b  = wtile / (QT*HI);

  f32x4 ae[4], ao[4];
  #pragma unroll
  for (int nt=0;nt<4;nt++){ ae[nt]=(f32x4){0.f,0.f,0.f,0.f}; ao[nt]=(f32x4){0.f,0.f,0.f,0.f}; }

  const uint4* bp4 = (const uint4*)bpack;

  #pragma unroll 1
  for (int ky=0; ky<3; ky++){
    int iy = y + ky - 1;
    if (iy < 0 || iy >= HI) continue;
    const bf16* rowp = in + ((size_t)(b*HI+iy)*WI)*64 + quad*8;
    #pragma unroll
    for (int c=0;c<2;c++){
      int qa = q0 + m;
      bf16x8 Au = load_frag(rowp + (size_t)qa*64 + c*32, true);
      bf16x8 As = load_frag(rowp + (size_t)(qa-1)*64 + c*32, qa >= 1);
      #pragma unroll
      for (int nt=0;nt<4;nt++){
        uint4 B0 = bp4[(((ky*3+0)*2+c)*4+nt)*64 + lane];
        uint4 B1 = bp4[(((ky*3+1)*2+c)*4+nt)*64 + lane];
        uint4 B2 = bp4[(((ky*3+2)*2+c)*4+nt)*64 + lane];
        ae[nt] = mfma16(As, B0, ae[nt]);
        ae[nt] = mfma16(Au, B2, ae[nt]);
        ao[nt] = mfma16(Au, B1, ao[nt]);
      }
    }
  }

  float4 bv = *(const float4*)(upb + m*4);
  size_t rowbase = ((size_t)b*HO + y)*WO;
  #pragma unroll
  for (int r=0;r<4;r++){
    int qq = q0 + quad*4 + r;
    {
      float g0 = gelu_f(ae[0][r] + bv.x);
      float g1 = gelu_f(ae[1][r] + bv.y);
      float g2 = gelu_f(ae[2][r] + bv.z);
      float g3 = gelu_f(ae[3][r] + bv.w);
      unsigned int lo = (unsigned int)b2u(f2b(g0)) | ((unsigned int)b2u(f2b(g1))<<16);
      unsigned int hi = (unsigned int)b2u(f2b(g2)) | ((unsigned int)b2u(f2b(g3))<<16);
      *(uint2*)(out + (rowbase + 2*qq)*64 + m*4) = make_uint2(lo,hi);
    }
    {
      float g0 = gelu_f(ao[0][r] + bv.x);
      float g1 = gelu_f(ao[1][r] + bv.y);
      float g2 = gelu_f(ao[2][r] + bv.z);
      float g3 = gelu_f(ao[3][r] + bv.w);
      unsigned int lo = (unsigned int)b2u(f2b(g0)) | ((unsigned int)b2u(f2b(g1))<<16);
      unsigned int hi = (unsigned int)b2u(f2b(g2)) | ((unsigned int)b2u(f2b(g3))<<16);
      *(uint2*)(out + (rowbase + 2*qq+1)*64 + m*4) = make_uint2(lo,hi);
    }
  }
}

// ---------------- maskloss, register form — step 0 only ------------------------
template<int STEP, int DIM, int HH, int WW, int TILES>
__global__ void maskloss_mfma(const bf16* __restrict__ feat, const bf16* __restrict__ mpack,
                              const float* __restrict__ mb, const float* __restrict__ img,
                              const float* __restrict__ masks_in, float* __restrict__ masks_out,
                              float* __restrict__ accbuf){
  __shared__ float llog[4][64][4];
  __shared__ float red[4][2];
  int lane = threadIdx.x & 63;
  int wv   = threadIdx.x >> 6;
  int wtile = swz8(blockIdx.x, gridDim.x)*4 + wv;
  int m = lane & 15, quad = lane >> 4;

  constexpr int TPR = WW/(16*TILES);
  int x0 = (wtile % TPR)*(16*TILES);
  int y  = (wtile / TPR) % HH;
  int b  = wtile / (TPR*HH);

  const uint4* bp4 = (const uint4*)mpack;

  #pragma unroll 1
  for (int t=0; t<TILES; t++){
    f32x4 acc4 = (f32x4){0.f,0.f,0.f,0.f};
    #pragma unroll
    for (int c=0;c<2;c++){
      bf16x8 afr[9];
      #pragma unroll
      for (int ky=0; ky<3; ky++){
        int iy = y + ky - 1;
        bool rowok = (iy >= 0) && (iy < HH);
        const bf16* rowp = feat + ((size_t)(b*HH+iy)*WW)*64 + quad*8 + c*32;
        #pragma unroll
        for (int kx=0; kx<3; kx++){
          int ix = x0 + t*16 + m + kx - 1;
          bool ok = rowok && (ix >= 0) && (ix < WW);
          afr[ky*3+kx] = load_frag(rowp + (size_t)ix*64, ok);
        }
      }
      #pragma unroll
      for (int tap=0; tap<9; tap++){
        uint4 bb = bp4[(tap*2+c)*64 + lane];
        acc4 = mfma16(afr[tap], bb, acc4);
      }
    }
    if (m < 4){
      #pragma unroll
      for (int r=0;r<4;r++) llog[wv][t*16 + quad*4 + r][m] = acc4[r] + mb[m];
    }
  }
  __syncthreads();

  float ent = 0.f, mse = 0.f;
  if (lane < 16*TILES){
    int p = lane; int xx = x0 + p;
    float l0 = llog[wv][p][0], l1 = llog[wv][p][1];
    float l2 = llog[wv][p][2], l3 = llog[wv][p][3];
    float mx = fmaxf(fmaxf(l0,l1), fmaxf(l2,l3));
    float e0=__expf(l0-mx), e1=__expf(l1-mx), e2=__expf(l2-mx), e3=__expf(l3-mx);
    float inv = __builtin_amdgcn_rcpf(e0+e1+e2+e3);
    float p0=e0*inv, p1=e1*inv, p2=e2*inv, p3=e3*inv;
    float sval = p1 + 2.f*p2 + 3.f*p3;

    constexpr int HM = (DIM==0)? HH/2 : HH;
    constexpr int WM = (DIM==0)? WW : WW/2;
    int my = (DIM==0)? (y>>1) : y;
    int mxi = (DIM==1)? (xx>>1) : xx;
    float mv = masks_in[((size_t)b*HM + my)*WM + mxi];
    masks_out[((size_t)b*HH + y)*WW + xx] = mv + 0.25f*sval;

    ent = -(p0*__logf(p0+1e-8f) + p1*__logf(p1+1e-8f) +
            p2*__logf(p2+1e-8f) + p3*__logf(p3+1e-8f));

    constexpr int FH = 256/HH, FW = 256/WW;
    float isum = 0.f;
    const float* ib = img + ((size_t)b*256 + y*FH)*256 + xx*FW;
    #pragma unroll
    for (int dy=0; dy<FH; dy++)
      #pragma unroll
      for (int dx=0; dx<FW; dx++) isum += ib[dy*256+dx];
    float img_ds = isum * (1.0f/(FH*FW));
    float d = sval*(1.0f/3.0f) - img_ds;
    mse = d*d;
  }

  #pragma unroll
  for (int off=1; off<64; off<<=1){
    ent += __shfl_xor(ent, off, 64);
    mse += __shfl_xor(mse, off, 64);
  }
  if (lane == 0){ red[wv][0] = ent; red[wv][1] = mse; }
  __syncthreads();
  if (threadIdx.x == 0){
    float e  = red[0][0] + red[1][0] + red[2][0] + red[3][0];
    float ms = red[0][1] + red[1][1] + red[2][1] + red[3][1];
    int slot = blockIdx.x & (NSLOT-1);
    atomicAdd(accbuf + (2*STEP  )*NSLOT + slot, e);
    atomicAdd(accbuf + (2*STEP+1)*NSLOT + slot, ms);
  }
}

// ---------------- maskloss via async LDS staging (WW >= 64) --------------------
template<int STEP, int DIM, int HH, int WW>
__global__ void maskloss_lds(const bf16* __restrict__ feat, const bf16* __restrict__ mpack,
                             const float* __restrict__ mb, const float* __restrict__ img,
                             const float* __restrict__ masks_in, float* __restrict__ masks_out,
                             float* __restrict__ accbuf){
  constexpr int NBrow = WW/64;
  constexpr int PITCH = 9216;                // 72 px * 128 B
  __shared__ __align__(16) char smem[3*PITCH];
  __shared__ float llog[4][16][4];
  __shared__ float red[4][2];
  int tid = threadIdx.x;
  int lane = tid & 63, wv = tid >> 6;
  int bi = swz8(blockIdx.x, gridDim.x);
  int x0 = (bi % NBrow)*64;
  int y  = (bi / NBrow) % HH;
  int b  = bi / (NBrow*HH);
  int m = lane & 15, quad = lane >> 4;

  bool rok[3];
  #pragma unroll
  for (int r=0;r<3;r++){ int iy=y+r-1; rok[r] = (iy>=0)&&(iy<HH); }

  for (int k = wv; k < 27; k += 4){
    int r = k/9, coff = (k%9)*1024;
    if (!rok[r]) continue;
    int iy = y + r - 1;
    const char* g = (const char*)(feat + ((size_t)(b*HH+iy)*WW + x0 - 1)*64)
                    + coff + lane*16;
    dma16(g, smem + r*PITCH + coff);
  }
  asm volatile("s_waitcnt vmcnt(0)" ::: "memory");
  __syncthreads();
  if (x0 == 0 && tid < 96)
    ((float*)(smem + (tid>>5)*PITCH))[tid & 31] = 0.f;
  if (x0 + 64 == WW && tid >= 128 && tid < 224){
    int t = tid - 128;
    ((float*)(smem + (t>>5)*PITCH + 65*128))[t & 31] = 0.f;
  }
  __syncthreads();

  const uint4* bp4 = (const uint4*)mpack;
  f32x4 accA = (f32x4){0.f,0.f,0.f,0.f};
  f32x4 accB = (f32x4){0.f,0.f,0.f,0.f};
  #pragma unroll 1
  for (int ky=0; ky<3; ky++){
    if (!rok[ky]) continue;
    const char* rowl = smem + ky*PITCH;
    #pragma unroll
    for (int kx=0; kx<3; kx++){
      int lp = wv*16 + m + kx;
      const char* pl = rowl + lp*128 + quad*16;
      bf16x8 a0 = __builtin_bit_cast(bf16x8, *(const uint4*)(pl));
      bf16x8 a1 = __builtin_bit_cast(bf16x8, *(const uint4*)(pl + 64));
      uint4 b0 = bp4[((ky*3+kx)*2+0)*64 + lane];
      uint4 b1 = bp4[((ky*3+kx)*2+1)*64 + lane];
      accA = mfma16(a0, b0, accA);
      accB = mfma16(a1, b1, accB);
    }
  }

  if (m < 4){
    #pragma unroll
    for (int r=0;r<4;r++) llog[wv][quad*4+r][m] = accA[r] + accB[r] + mb[m];
  }
  __syncthreads();

  float ent = 0.f, mse = 0.f;
  if (lane < 16){
    int p = lane; int xx = x0 + wv*16 + p;
    float l0 = llog[wv][p][0], l1 = llog[wv][p][1];
    float l2 = llog[wv][p][2], l3 = llog[wv][p][3];
    float mx = fmaxf(fmaxf(l0,l1), fmaxf(l2,l3));
    float e0=__expf(l0-mx), e1=__expf(l1-mx), e2=__expf(l2-mx), e3=__expf(l3-mx);
    float inv = __builtin_amdgcn_rcpf(e0+e1+e2+e3);
    float p0=e0*inv, p1=e1*inv, p2=e2*inv, p3=e3*inv;
    float sval = p1 + 2.f*p2 + 3.f*p3;

    constexpr int HM = (DIM==0)? HH/2 : HH;
    constexpr int WM = (DIM==0)? WW : WW/2;
    int my = (DIM==0)? (y>>1) : y;
    int mxi = (DIM==1)? (xx>>1) : xx;
    float mv = masks_in[((size_t)b*HM + my)*WM + mxi];
    masks_out[((size_t)b*HH + y)*WW + xx] = mv + 0.25f*sval;

    ent = -(p0*__logf(p0+1e-8f) + p1*__logf(p1+1e-8f) +
            p2*__logf(p2+1e-8f) + p3*__logf(p3+1e-8f));

    constexpr int FH = 256/HH, FW = 256/WW;
    float isum = 0.f;
    const float* ib = img + ((size_t)b*256 + y*FH)*256 + xx*FW;
    #pragma unroll
    for (int dy=0; dy<FH; dy++)
      #pragma unroll
      for (int dx=0; dx<FW; dx++) isum += ib[dy*256+dx];
    float img_ds = isum * (1.0f/(FH*FW));
    float d = sval*(1.0f/3.0f) - img_ds;
    mse = d*d;
  }

  #pragma unroll
  for (int off=1; off<64; off<<=1){
    ent += __shfl_xor(ent, off, 64);
    mse += __shfl_xor(mse, off, 64);
  }
  if (lane == 0){ red[wv][0] = ent; red[wv][1] = mse; }
  __syncthreads();
  if (threadIdx.x == 0){
    float e  = red[0][0] + red[1][0] + red[2][0] + red[3][0];
    float ms = red[0][1] + red[1][1] + red[2][1] + red[3][1];
    int slot = blockIdx.x & (NSLOT-1);
    atomicAdd(accbuf + (2*STEP  )*NSLOT + slot, e);
    atomicAdd(accbuf + (2*STEP+1)*NSLOT + slot, ms);
  }
}

__global__ void finalize_kernel(const float* __restrict__ acc, float* __restrict__ out){
  int lane = threadIdx.x & 63;
  float v[12];
  #pragma unroll
  for (int i=0;i<12;i++){
    float x = acc[i*NSLOT + lane];
    #pragma unroll
    for (int off=1; off<64; off<<=1) x += __shfl_xor(x, off, 64);
    v[i] = x;
  }
  if (lane == 0){
    const float lw[6] = {0.1f,0.1f,0.5f,0.5f,1.0f,1.0f};
    const float nn[6] = {16384.f,32768.f,65536.f,131072.f,262144.f,524288.f};
    float L=0.f;
    for (int i=0;i<6;i++) L += lw[i]*((v[2*i] + v[2*i+1])/nn[i]);
    out[0]=L;
  }
}

extern "C" void kernel_launch(void* const* d_in, const int* in_sizes, int n_in,
                              void* d_out, int out_size, void* d_ws, size_t ws_size,
                              hipStream_t stream){
  const float* image  = (const float*)d_in[0];
  const float* w1=(const float*)d_in[2];  const float* b1=(const float*)d_in[3];
  const float* w2=(const float*)d_in[4];  const float* b2=(const float*)d_in[5];
  const float* w3=(const float*)d_in[6];  const float* b3=(const float*)d_in[7];
  const float* w4=(const float*)d_in[8];  const float* b4=(const float*)d_in[9];
  const float* upw=(const float*)d_in[10];const float* upb=(const float*)d_in[11];
  const float* mw=(const float*)d_in[12]; const float* mb=(const float*)d_in[13];
  const float* masks0=(const float*)d_in[14];
  float* out = (float*)d_out;

  char* ws = (char*)d_ws;
  size_t off = 0;
  auto alloc = [&](size_t bytes)->char*{
    char* p = ws + off; off += (bytes + 255) & ~(size_t)255; return p;
  };
  bf16* enc1  = (bf16*)alloc((size_t)8*256*256*16*2);
  bf16* enc2  = (bf16*)alloc((size_t)8*128*128*16*2);
  bf16* enc3  = (bf16*)alloc((size_t)8*64*64*32*2);
  bf16* featA = (bf16*)alloc((size_t)8*256*256*64*2);
  bf16* featB = (bf16*)alloc((size_t)8*256*128*64*2);
  float* mbA  = (float*)alloc((size_t)8*256*128*4);
  float* mbB  = (float*)alloc((size_t)8*128*128*4);
  bf16* packU = (bf16*)alloc((size_t)9*2*4*64*8*2);
  bf16* packM = (bf16*)alloc((size_t)9*2*64*8*2);
  float* acc  = (float*)alloc(12*NSLOT*sizeof(float));

  hipMemsetAsync(acc, 0, 12*NSLOT*sizeof(float), stream);

  repack_up  <<<144,256,0,stream>>>(upw, packU);
  repack_mask<<< 36,256,0,stream>>>(mw,  packM);

  // encoder — SUB chosen so every trio has >=512 blocks:
  trio_kernel<float,1,16,1,1,256,256><<<8*256*256/256,256,0,stream>>>(image,w1,b1,enc1);
  trio_kernel<bf16,16,16,2,2,256,256><<<8*128*128*2/256,256,0,stream>>>(enc1,w2,b2,enc2);
  trio_kernel<bf16,16,32,8,2,128,128><<<8*64*64*8/256,256,0,stream>>>(enc2,w3,b3,enc3);
  trio_kernel<bf16,32,64,16,2,64,64><<<8*32*32*16/256,256,0,stream>>>(enc3,w4,b4,featA);

  // step 0: (32,32) -> (64,32)
  upconv_dim0<32,32><<<128,256,0,stream>>>(featA,packU,upb,featB);
  maskloss_mfma<0,0,64,32,2><<<128,256,0,stream>>>(featB,packM,mb,image,masks0,mbA,acc);
  // step 1: (64,32) -> (64,64)
  upconv_dim1<64,32><<<256,256,0,stream>>>(featB,packU,upb,featA);
  maskloss_lds<1,1,64,64><<<512,256,0,stream>>>(featA,packM,mb,image,mbA,mbB,acc);
  // step 2: (64,64) -> (128,64)
  upconv_dim0<64,64><<<512,256,0,stream>>>(featA,packU,upb,featB);
  maskloss_lds<2,0,128,64><<<1024,256,0,stream>>>(featB,packM,mb,image,mbB,mbA,acc);
  // step 3: (128,64) -> (128,128)
  upconv_dim1<128,64><<<1024,256,0,stream>>>(featB,packU,upb,featA);
  maskloss_lds<3,1,128,128><<<2048,256,0,stream>>>(featA,packM,mb,image,mbA,mbB,acc);
  // step 4: (128,128) -> (256,128)
  upconv_dim0<128,128><<<2048,256,0,stream>>>(featA,packU,upb,featB);
  maskloss_lds<4,0,256,128><<<4096,256,0,stream>>>(featB,packM,mb,image,mbB,mbA,acc);
  // step 5: (256,128) -> (256,256)
  upconv_dim1<256,128><<<4096,256,0,stream>>>(featB,packU,upb,featA);
  maskloss_lds<5,1,256,256><<<8192,256,0,stream>>>(featA,packM,mb,image,mbA,out+1,acc);

  finalize_kernel<<<1,64,0,stream>>>(acc,out);
}

// Round 16
// 466.188 us; speedup vs baseline: 1.1622x; 1.0178x over previous
//
#include <hip/hip_runtime.h>
#include <hip/hip_bf16.h>
#include <math.h>

typedef __hip_bfloat16 bf16;
typedef float f32x4 __attribute__((ext_vector_type(4)));
typedef __bf16 bf16x8 __attribute__((ext_vector_type(8)));

#define DEV __device__ __forceinline__

DEV float to_f(float v){ return v; }
DEV float to_f(bf16 v){ return __bfloat162float(v); }
DEV bf16 f2b(float v){ return __float2bfloat16(v); }
DEV unsigned short b2u(bf16 v){ return __builtin_bit_cast(unsigned short, v); }

DEV float gelu_f(float x){
  float z = 1.5957691216057308f*(x + 0.044715f*x*x*x);
  float e = __expf(-z);
  return x * __builtin_amdgcn_rcpf(1.0f + e);
}

DEV bf16x8 load_frag(const bf16* p, bool ok){
  uint4 u = make_uint4(0u,0u,0u,0u);
  if (ok) u = *(const uint4*)p;
  return __builtin_bit_cast(bf16x8, u);
}

DEV f32x4 mfma16(bf16x8 a, uint4 b, f32x4 c){
  return __builtin_amdgcn_mfma_f32_16x16x32_bf16(a, __builtin_bit_cast(bf16x8, b), c, 0, 0, 0);
}

DEV int swz8(int blk, int n){
  return (blk & 7) * (n >> 3) + (blk >> 3);
}

// async global->LDS DMA, 16 B per lane; lds dest wave-uniform base.
DEV void dma16(const void* g, void* l){
  __builtin_amdgcn_global_load_lds(
      (const __attribute__((address_space(1))) unsigned int*)g,
      (__attribute__((address_space(3))) unsigned int*)l,
      16, 0, 0);
}

#define NSLOT 64

// ---------------- encoder Conv_trio -------------------------------------------
template<typename TIN, int CIN, int COUT, int SUB, int STRIDE, int HI, int WI>
__global__ void trio_kernel(const TIN* __restrict__ in, const float* __restrict__ w,
                            const float* __restrict__ bias, bf16* __restrict__ out){
  constexpr int HO = HI/STRIDE, WO = WI/STRIDE;
  constexpr int CO_PER = COUT/SUB;
  int gtid = blockIdx.x*blockDim.x + threadIdx.x;
  int sub = gtid % SUB;
  int pix = gtid / SUB;
  int b = pix / (HO*WO); int rem = pix % (HO*WO);
  int y = rem / WO, x = rem % WO;

  float acc[CO_PER];
  #pragma unroll
  for (int j=0;j<CO_PER;j++) acc[j]=0.f;

  for (int ky=0;ky<3;ky++){
    int iy = (STRIDE==1) ? (y+ky-1) : (2*y+ky);
    if (iy<0 || iy>=HI) continue;
    for (int kx=0;kx<3;kx++){
      int ix = (STRIDE==1) ? (x+kx-1) : (2*x+kx);
      if (ix<0 || ix>=WI) continue;
      const TIN* ip = in + ((size_t)(b*HI+iy)*WI+ix)*CIN;
      const float* wp = w + ((ky*3+kx)*CIN)*COUT + sub*CO_PER;
      if constexpr (sizeof(TIN)==2 && (CIN%8)==0){
        #pragma unroll
        for (int v=0; v<CIN/8; v++){
          uint4 u = *(const uint4*)((const bf16*)ip + v*8);
          bf16x8 ch = __builtin_bit_cast(bf16x8, u);
          #pragma unroll
          for (int j=0;j<8;j++){
            float a = (float)ch[j];
            const float4* w4 = (const float4*)(wp + (size_t)(v*8+j)*COUT);
            #pragma unroll
            for (int q2=0;q2<CO_PER/4;q2++){
              float4 ww = w4[q2];
              acc[4*q2+0] += a*ww.x; acc[4*q2+1] += a*ww.y;
              acc[4*q2+2] += a*ww.z; acc[4*q2+3] += a*ww.w;
            }
          }
        }
      } else {
        #pragma unroll 4
        for (int ci=0; ci<CIN; ci++){
          float a = to_f(ip[ci]);
          const float4* w4 = (const float4*)(wp + (size_t)ci*COUT);
          #pragma unroll
          for (int j=0;j<CO_PER/4;j++){
            float4 ww = w4[j];
            acc[4*j+0] += a*ww.x; acc[4*j+1] += a*ww.y;
            acc[4*j+2] += a*ww.z; acc[4*j+3] += a*ww.w;
          }
        }
      }
    }
  }

  float s1=0.f, s2=0.f;
  #pragma unroll
  for (int j=0;j<CO_PER;j++){
    acc[j] += bias[sub*CO_PER+j];
    s1 += acc[j]; s2 += acc[j]*acc[j];
  }
  #pragma unroll
  for (int off=1; off<SUB; off<<=1){
    s1 += __shfl_xor(s1,off,64);
    s2 += __shfl_xor(s2,off,64);
  }
  float mu  = s1*(1.0f/COUT);
  float var = s2*(1.0f/COUT) - mu*mu;
  float sc  = rsqrtf(var + 1e-6f);

  bf16* op = out + (size_t)pix*COUT + sub*CO_PER;
  #pragma unroll
  for (int j=0;j<CO_PER;j++) op[j] = f2b(gelu_f((acc[j]-mu)*sc));
}

// ---------------- weight repack -----------------------------------------------
__global__ void repack_up(const float* __restrict__ w, bf16* __restrict__ bp){
  int v = blockIdx.x*256 + threadIdx.x;
  if (v >= 9*2*4*64*8) return;
  int j = v & 7; int lane = (v>>3)&63; int nt = (v>>9)&3; int c = (v>>11)&1; int tap = v>>12;
  int ci = c*32 + (lane>>4)*8 + j;
  int co = (lane&15)*4 + nt;
  bp[v] = f2b(w[(tap*64+ci)*64 + co]);
}

__global__ void repack_mask(const float* __restrict__ w, bf16* __restrict__ bp){
  int v = blockIdx.x*256 + threadIdx.x;
  if (v >= 9*2*64*8) return;
  int j = v & 7; int lane = (v>>3)&63; int c = (v>>9)&1; int tap = v>>10;
  int ci = c*32 + (lane>>4)*8 + j;
  int n = lane & 15;
  bp[v] = (n < 4) ? f2b(w[(tap*64+ci)*4 + n]) : f2b(0.0f);
}

// ------------- conv_transpose, stride-2 along y (DIM=0) -----------------------
// B hoisted over the 2 pixel-tiles: per (s,ut,c) load A[t0],A[t1], then per-nt
// one B load feeds 2 MFMAs (B:MFMA 1:2, was 1:1).
template<int HI, int WI>
__global__ void upconv_dim0(const bf16* __restrict__ in, const bf16* __restrict__ bpack,
                            const float* __restrict__ upb, bf16* __restrict__ out){
  constexpr int HO = 2*HI, WO = WI, XT = WI/32;
  int lane = threadIdx.x & 63, wv = threadIdx.x >> 6;
  int wtile = swz8(blockIdx.x, gridDim.x)*4 + wv;
  int m = lane & 15, quad = lane >> 4;

  int x0 = (wtile % XT)*32;
  int o  = (wtile / XT) % HO;
  int b  = wtile / (XT*HO);

  int q = o >> 1;
  int stk[2], stq[2]; int nst;
  if (o & 1){ stk[0]=1; stq[0]=q; nst=1; }
  else {
    nst = 0;
    if (q >= 1){ stk[0]=0; stq[0]=q-1; nst=1; }
    stk[nst]=2; stq[nst]=q; nst++;
  }

  f32x4 acc[2][4];
  #pragma unroll
  for (int t=0;t<2;t++)
    #pragma unroll
    for (int nt=0;nt<4;nt++) acc[t][nt] = (f32x4){0.f,0.f,0.f,0.f};

  const uint4* bp4 = (const uint4*)bpack;

  #pragma unroll 1
  for (int s=0; s<nst; s++){
    int kyt = stk[s];
    const bf16* rowp = in + ((size_t)(b*HI+stq[s])*WI)*64 + quad*8;
    #pragma unroll
    for (int ut=0; ut<3; ut++){
      #pragma unroll
      for (int c=0;c<2;c++){
        int ix0 = x0 + m - 1 + ut;
        int ix1 = ix0 + 16;
        bf16x8 a0 = load_frag(rowp + (size_t)ix0*64 + c*32, ix0>=0 && ix0<WI);
        bf16x8 a1 = load_frag(rowp + (size_t)ix1*64 + c*32, ix1>=0 && ix1<WI);
        #pragma unroll
        for (int nt=0;nt<4;nt++){
          uint4 Bq = bp4[(((kyt*3+ut)*2+c)*4+nt)*64 + lane];
          acc[0][nt] = mfma16(a0, Bq, acc[0][nt]);
          acc[1][nt] = mfma16(a1, Bq, acc[1][nt]);
        }
      }
    }
  }

  float4 bv = *(const float4*)(upb + m*4);
  size_t rowbase = ((size_t)b*HO + o)*WO;
  #pragma unroll
  for (int t=0;t<2;t++){
    #pragma unroll
    for (int r=0;r<4;r++){
      int p = x0 + t*16 + quad*4 + r;
      float g0 = gelu_f(acc[t][0][r] + bv.x);
      float g1 = gelu_f(acc[t][1][r] + bv.y);
      float g2 = gelu_f(acc[t][2][r] + bv.z);
      float g3 = gelu_f(acc[t][3][r] + bv.w);
      unsigned int lo = (unsigned int)b2u(f2b(g0)) | ((unsigned int)b2u(f2b(g1))<<16);
      unsigned int hi = (unsigned int)b2u(f2b(g2)) | ((unsigned int)b2u(f2b(g3))<<16);
      *(uint2*)(out + (rowbase + p)*64 + m*4) = make_uint2(lo,hi);
    }
  }
}

// ------------- conv_transpose dim1, register form — step 1 (WI=32) only -------
template<int HI, int WI>
__global__ void upconv_dim1(const bf16* __restrict__ in, const bf16* __restrict__ bpack,
                            const float* __restrict__ upb, bf16* __restrict__ out){
  constexpr int HO = HI, WO = 2*WI, QT = WI/16;
  int lane = threadIdx.x & 63, wv = threadIdx.x >> 6;
  int wtile = swz8(blockIdx.x, gridDim.x)*4 + wv;
  int m = lane & 15, quad = lane >> 4;

  int q0 = (wtile % QT)*16;
  int y  = (wtile / QT) % HI;
  int b  = wtile / (QT*HI);

  f32x4 ae[4], ao[4];
  #pragma unroll
  for (int nt=0;nt<4;nt++){ ae[nt]=(f32x4){0.f,0.f,0.f,0.f}; ao[nt]=(f32x4){0.f,0.f,0.f,0.f}; }

  const uint4* bp4 = (const uint4*)bpack;

  #pragma unroll 1
  for (int ky=0; ky<3; ky++){
    int iy = y + ky - 1;
    if (iy < 0 || iy >= HI) continue;
    const bf16* rowp = in + ((size_t)(b*HI+iy)*WI)*64 + quad*8;
    #pragma unroll
    for (int c=0;c<2;c++){
      int qa = q0 + m;
      bf16x8 Au = load_frag(rowp + (size_t)qa*64 + c*32, true);
      bf16x8 As = load_frag(rowp + (size_t)(qa-1)*64 + c*32, qa >= 1);
      #pragma unroll
      for (int nt=0;nt<4;nt++){
        uint4 B0 = bp4[(((ky*3+0)*2+c)*4+nt)*64 + lane];
        uint4 B1 = bp4[(((ky*3+1)*2+c)*4+nt)*64 + lane];
        uint4 B2 = bp4[(((ky*3+2)*2+c)*4+nt)*64 + lane];
        ae[nt] = mfma16(As, B0, ae[nt]);
        ae[nt] = mfma16(Au, B2, ae[nt]);
        ao[nt] = mfma16(Au, B1, ao[nt]);
      }
    }
  }

  float4 bv = *(const float4*)(upb + m*4);
  size_t rowbase = ((size_t)b*HO + y)*WO;
  #pragma unroll
  for (int r=0;r<4;r++){
    int qq = q0 + quad*4 + r;
    {
      float g0 = gelu_f(ae[0][r] + bv.x);
      float g1 = gelu_f(ae[1][r] + bv.y);
      float g2 = gelu_f(ae[2][r] + bv.z);
      float g3 = gelu_f(ae[3][r] + bv.w);
      unsigned int lo = (unsigned int)b2u(f2b(g0)) | ((unsigned int)b2u(f2b(g1))<<16);
      unsigned int hi = (unsigned int)b2u(f2b(g2)) | ((unsigned int)b2u(f2b(g3))<<16);
      *(uint2*)(out + (rowbase + 2*qq)*64 + m*4) = make_uint2(lo,hi);
    }
    {
      float g0 = gelu_f(ao[0][r] + bv.x);
      float g1 = gelu_f(ao[1][r] + bv.y);
      float g2 = gelu_f(ao[2][r] + bv.z);
      float g3 = gelu_f(ao[3][r] + bv.w);
      unsigned int lo = (unsigned int)b2u(f2b(g0)) | ((unsigned int)b2u(f2b(g1))<<16);
      unsigned int hi = (unsigned int)b2u(f2b(g2)) | ((unsigned int)b2u(f2b(g3))<<16);
      *(uint2*)(out + (rowbase + 2*qq+1)*64 + m*4) = make_uint2(lo,hi);
    }
  }
}

// ------------- conv_transpose dim1 via async LDS staging (WI >= 64) -----------
// Block = one output row y, 64 q-cols (128 outputs). Stage rows y-1..y+1 x 72 px
// via global_load_lds; A from ds_read_b128. dim1 needs only the LEFT halo (q-1).
template<int HI, int WI>
__global__ void upconv_dim1_lds(const bf16* __restrict__ in, const bf16* __restrict__ bpack,
                                const float* __restrict__ upb, bf16* __restrict__ out){
  constexpr int HO = HI, WO = 2*WI, NBq = WI/64;
  constexpr int PITCH = 9216;                 // 72 px * 128 B
  __shared__ __align__(16) char smem[3*PITCH];
  int tid = threadIdx.x, lane = tid & 63, wv = tid >> 6;
  int bi = swz8(blockIdx.x, gridDim.x);
  int q0 = (bi % NBq)*64;
  int y  = (bi / NBq) % HI;
  int b  = bi / (NBq*HI);
  int m = lane & 15, quad = lane >> 4;

  bool rok[3];
  #pragma unroll
  for (int r=0;r<3;r++){ int iy=y+r-1; rok[r] = (iy>=0)&&(iy<HI); }

  for (int k = wv; k < 27; k += 4){
    int r = k/9, coff = (k%9)*1024;
    if (!rok[r]) continue;
    int iy = y + r - 1;
    const char* g = (const char*)(in + ((size_t)(b*HI+iy)*WI + q0 - 1)*64)
                    + coff + lane*16;
    dma16(g, smem + r*PITCH + coff);
  }
  asm volatile("s_waitcnt vmcnt(0)" ::: "memory");
  __syncthreads();
  if (q0 == 0 && tid < 96)
    ((float*)(smem + (tid>>5)*PITCH))[tid & 31] = 0.f;   // zero q=-1 halo col
  __syncthreads();

  f32x4 ae[4], ao[4];
  #pragma unroll
  for (int nt=0;nt<4;nt++){ ae[nt]=(f32x4){0.f,0.f,0.f,0.f}; ao[nt]=(f32x4){0.f,0.f,0.f,0.f}; }

  const uint4* bp4 = (const uint4*)bpack;

  #pragma unroll 1
  for (int ky=0; ky<3; ky++){
    if (!rok[ky]) continue;
    const char* rowl = smem + ky*PITCH;
    #pragma unroll
    for (int c=0;c<2;c++){
      int j = wv*16 + m + 1;                   // col for q = q0 + wv*16 + m
      bf16x8 Au = __builtin_bit_cast(bf16x8, *(const uint4*)(rowl + (size_t)j*128 + quad*16 + c*64));
      bf16x8 As = __builtin_bit_cast(bf16x8, *(const uint4*)(rowl + (size_t)(j-1)*128 + quad*16 + c*64));
      #pragma unroll
      for (int nt=0;nt<4;nt++){
        uint4 B0 = bp4[(((ky*3+0)*2+c)*4+nt)*64 + lane];
        uint4 B1 = bp4[(((ky*3+1)*2+c)*4+nt)*64 + lane];
        uint4 B2 = bp4[(((ky*3+2)*2+c)*4+nt)*64 + lane];
        ae[nt] = mfma16(As, B0, ae[nt]);
        ae[nt] = mfma16(Au, B2, ae[nt]);
        ao[nt] = mfma16(Au, B1, ao[nt]);
      }
    }
  }

  float4 bv = *(const float4*)(upb + m*4);
  size_t rowbase = ((size_t)b*HO + y)*WO;
  #pragma unroll
  for (int r=0;r<4;r++){
    int qq = q0 + wv*16 + quad*4 + r;
    {
      float g0 = gelu_f(ae[0][r] + bv.x);
      float g1 = gelu_f(ae[1][r] + bv.y);
      float g2 = gelu_f(ae[2][r] + bv.z);
      float g3 = gelu_f(ae[3][r] + bv.w);
      unsigned int lo = (unsigned int)b2u(f2b(g0)) | ((unsigned int)b2u(f2b(g1))<<16);
      unsigned int hi = (unsigned int)b2u(f2b(g2)) | ((unsigned int)b2u(f2b(g3))<<16);
      *(uint2*)(out + (rowbase + 2*qq)*64 + m*4) = make_uint2(lo,hi);
    }
    {
      float g0 = gelu_f(ao[0][r] + bv.x);
      float g1 = gelu_f(ao[1][r] + bv.y);
      float g2 = gelu_f(ao[2][r] + bv.z);
      float g3 = gelu_f(ao[3][r] + bv.w);
      unsigned int lo = (unsigned int)b2u(f2b(g0)) | ((unsigned int)b2u(f2b(g1))<<16);
      unsigned int hi = (unsigned int)b2u(f2b(g2)) | ((unsigned int)b2u(f2b(g3))<<16);
      *(uint2*)(out + (rowbase + 2*qq+1)*64 + m*4) = make_uint2(lo,hi);
    }
  }
}

// ---------------- maskloss, register form — step 0 only ------------------------
template<int STEP, int DIM, int HH, int WW, int TILES>
__global__ void maskloss_mfma(const bf16* __restrict__ feat, const bf16* __restrict__ mpack,
                              const float* __restrict__ mb, const float* __restrict__ img,
                              const float* __restrict__ masks_in, float* __restrict__ masks_out,
                              float* __restrict__ accbuf){
  __shared__ float llog[4][64][4];
  __shared__ float red[4][2];
  int lane = threadIdx.x & 63;
  int wv   = threadIdx.x >> 6;
  int wtile = swz8(blockIdx.x, gridDim.x)*4 + wv;
  int m = lane & 15, quad = lane >> 4;

  constexpr int TPR = WW/(16*TILES);
  int x0 = (wtile % TPR)*(16*TILES);
  int y  = (wtile / TPR) % HH;
  int b  = wtile / (TPR*HH);

  const uint4* bp4 = (const uint4*)mpack;

  #pragma unroll 1
  for (int t=0; t<TILES; t++){
    f32x4 acc4 = (f32x4){0.f,0.f,0.f,0.f};
    #pragma unroll
    for (int c=0;c<2;c++){
      bf16x8 afr[9];
      #pragma unroll
      for (int ky=0; ky<3; ky++){
        int iy = y + ky - 1;
        bool rowok = (iy >= 0) && (iy < HH);
        const bf16* rowp = feat + ((size_t)(b*HH+iy)*WW)*64 + quad*8 + c*32;
        #pragma unroll
        for (int kx=0; kx<3; kx++){
          int ix = x0 + t*16 + m + kx - 1;
          bool ok = rowok && (ix >= 0) && (ix < WW);
          afr[ky*3+kx] = load_frag(rowp + (size_t)ix*64, ok);
        }
      }
      #pragma unroll
      for (int tap=0; tap<9; tap++){
        uint4 bb = bp4[(tap*2+c)*64 + lane];
        acc4 = mfma16(afr[tap], bb, acc4);
      }
    }
    if (m < 4){
      #pragma unroll
      for (int r=0;r<4;r++) llog[wv][t*16 + quad*4 + r][m] = acc4[r] + mb[m];
    }
  }
  __syncthreads();

  float ent = 0.f, mse = 0.f;
  if (lane < 16*TILES){
    int p = lane; int xx = x0 + p;
    float l0 = llog[wv][p][0], l1 = llog[wv][p][1];
    float l2 = llog[wv][p][2], l3 = llog[wv][p][3];
    float mx = fmaxf(fmaxf(l0,l1), fmaxf(l2,l3));
    float e0=__expf(l0-mx), e1=__expf(l1-mx), e2=__expf(l2-mx), e3=__expf(l3-mx);
    float inv = __builtin_amdgcn_rcpf(e0+e1+e2+e3);
    float p0=e0*inv, p1=e1*inv, p2=e2*inv, p3=e3*inv;
    float sval = p1 + 2.f*p2 + 3.f*p3;

    constexpr int HM = (DIM==0)? HH/2 : HH;
    constexpr int WM = (DIM==0)? WW : WW/2;
    int my = (DIM==0)? (y>>1) : y;
    int mxi = (DIM==1)? (xx>>1) : xx;
    float mv = masks_in[((size_t)b*HM + my)*WM + mxi];
    masks_out[((size_t)b*HH + y)*WW + xx] = mv + 0.25f*sval;

    ent = -(p0*__logf(p0+1e-8f) + p1*__logf(p1+1e-8f) +
            p2*__logf(p2+1e-8f) + p3*__logf(p3+1e-8f));

    constexpr int FH = 256/HH, FW = 256/WW;
    float isum = 0.f;
    const float* ib = img + ((size_t)b*256 + y*FH)*256 + xx*FW;
    #pragma unroll
    for (int dy=0; dy<FH; dy++)
      #pragma unroll
      for (int dx=0; dx<FW; dx++) isum += ib[dy*256+dx];
    float img_ds = isum * (1.0f/(FH*FW));
    float d = sval*(1.0f/3.0f) - img_ds;
    mse = d*d;
  }

  #pragma unroll
  for (int off=1; off<64; off<<=1){
    ent += __shfl_xor(ent, off, 64);
    mse += __shfl_xor(mse, off, 64);
  }
  if (lane == 0){ red[wv][0] = ent; red[wv][1] = mse; }
  __syncthreads();
  if (threadIdx.x == 0){
    float e  = red[0][0] + red[1][0] + red[2][0] + red[3][0];
    float ms = red[0][1] + red[1][1] + red[2][1] + red[3][1];
    int slot = blockIdx.x & (NSLOT-1);
    atomicAdd(accbuf + (2*STEP  )*NSLOT + slot, e);
    atomicAdd(accbuf + (2*STEP+1)*NSLOT + slot, ms);
  }
}

// ---------------- maskloss via async LDS staging (WW >= 64) --------------------
template<int STEP, int DIM, int HH, int WW>
__global__ void maskloss_lds(const bf16* __restrict__ feat, const bf16* __restrict__ mpack,
                             const float* __restrict__ mb, const float* __restrict__ img,
                             const float* __restrict__ masks_in, float* __restrict__ masks_out,
                             float* __restrict__ accbuf){
  constexpr int NBrow = WW/64;
  constexpr int PITCH = 9216;                // 72 px * 128 B
  __shared__ __align__(16) char smem[3*PITCH];
  __shared__ float llog[4][16][4];
  __shared__ float red[4][2];
  int tid = threadIdx.x;
  int lane = tid & 63, wv = tid >> 6;
  int bi = swz8(blockIdx.x, gridDim.x);
  int x0 = (bi % NBrow)*64;
  int y  = (bi / NBrow) % HH;
  int b  = bi / (NBrow*HH);
  int m = lane & 15, quad = lane >> 4;

  bool rok[3];
  #pragma unroll
  for (int r=0;r<3;r++){ int iy=y+r-1; rok[r] = (iy>=0)&&(iy<HH); }

  for (int k = wv; k < 27; k += 4){
    int r = k/9, coff = (k%9)*1024;
    if (!rok[r]) continue;
    int iy = y + r - 1;
    const char* g = (const char*)(feat + ((size_t)(b*HH+iy)*WW + x0 - 1)*64)
                    + coff + lane*16;
    dma16(g, smem + r*PITCH + coff);
  }
  asm volatile("s_waitcnt vmcnt(0)" ::: "memory");
  __syncthreads();
  if (x0 == 0 && tid < 96)
    ((float*)(smem + (tid>>5)*PITCH))[tid & 31] = 0.f;
  if (x0 + 64 == WW && tid >= 128 && tid < 224){
    int t = tid - 128;
    ((float*)(smem + (t>>5)*PITCH + 65*128))[t & 31] = 0.f;
  }
  __syncthreads();

  const uint4* bp4 = (const uint4*)mpack;
  f32x4 accA = (f32x4){0.f,0.f,0.f,0.f};
  f32x4 accB = (f32x4){0.f,0.f,0.f,0.f};
  #pragma unroll 1
  for (int ky=0; ky<3; ky++){
    if (!rok[ky]) continue;
    const char* rowl = smem + ky*PITCH;
    #pragma unroll
    for (int kx=0; kx<3; kx++){
      int lp = wv*16 + m + kx;
      const char* pl = rowl + lp*128 + quad*16;
      bf16x8 a0 = __builtin_bit_cast(bf16x8, *(const uint4*)(pl));
      bf16x8 a1 = __builtin_bit_cast(bf16x8, *(const uint4*)(pl + 64));
      uint4 b0 = bp4[((ky*3+kx)*2+0)*64 + lane];
      uint4 b1 = bp4[((ky*3+kx)*2+1)*64 + lane];
      accA = mfma16(a0, b0, accA);
      accB = mfma16(a1, b1, accB);
    }
  }

  if (m < 4){
    #pragma unroll
    for (int r=0;r<4;r++) llog[wv][quad*4+r][m] = accA[r] + accB[r] + mb[m];
  }
  __syncthreads();

  float ent = 0.f, mse = 0.f;
  if (lane < 16){
    int p = lane; int xx = x0 + wv*16 + p;
    float l0 = llog[wv][p][0], l1 = llog[wv][p][1];
    float l2 = llog[wv][p][2], l3 = llog[wv][p][3];
    float mx = fmaxf(fmaxf(l0,l1), fmaxf(l2,l3));
    float e0=__expf(l0-mx), e1=__expf(l1-mx), e2=__expf(l2-mx), e3=__expf(l3-mx);
    float inv = __builtin_amdgcn_rcpf(e0+e1+e2+e3);
    float p0=e0*inv, p1=e1*inv, p2=e2*inv, p3=e3*inv;
    float sval = p1 + 2.f*p2 + 3.f*p3;

    constexpr int HM = (DIM==0)? HH/2 : HH;
    constexpr int WM = (DIM==0)? WW : WW/2;
    int my = (DIM==0)? (y>>1) : y;
    int mxi = (DIM==1)? (xx>>1) : xx;
    float mv = masks_in[((size_t)b*HM + my)*WM + mxi];
    masks_out[((size_t)b*HH + y)*WW + xx] = mv + 0.25f*sval;

    ent = -(p0*__logf(p0+1e-8f) + p1*__logf(p1+1e-8f) +
            p2*__logf(p2+1e-8f) + p3*__logf(p3+1e-8f));

    constexpr int FH = 256/HH, FW = 256/WW;
    float isum = 0.f;
    const float* ib = img + ((size_t)b*256 + y*FH)*256 + xx*FW;
    #pragma unroll
    for (int dy=0; dy<FH; dy++)
      #pragma unroll
      for (int dx=0; dx<FW; dx++) isum += ib[dy*256+dx];
    float img_ds = isum * (1.0f/(FH*FW));
    float d = sval*(1.0f/3.0f) - img_ds;
    mse = d*d;
  }

  #pragma unroll
  for (int off=1; off<64; off<<=1){
    ent += __shfl_xor(ent, off, 64);
    mse += __shfl_xor(mse, off, 64);
  }
  if (lane == 0){ red[wv][0] = ent; red[wv][1] = mse; }
  __syncthreads();
  if (threadIdx.x == 0){
    float e  = red[0][0] + red[1][0] + red[2][0] + red[3][0];
    float ms = red[0][1] + red[1][1] + red[2][1] + red[3][1];
    int slot = blockIdx.x & (NSLOT-1);
    atomicAdd(accbuf + (2*STEP  )*NSLOT + slot, e);
    atomicAdd(accbuf + (2*STEP+1)*NSLOT + slot, ms);
  }
}

__global__ void finalize_kernel(const float* __restrict__ acc, float* __restrict__ out){
  int lane = threadIdx.x & 63;
  float v[12];
  #pragma unroll
  for (int i=0;i<12;i++){
    float x = acc[i*NSLOT + lane];
    #pragma unroll
    for (int off=1; off<64; off<<=1) x += __shfl_xor(x, off, 64);
    v[i] = x;
  }
  if (lane == 0){
    const float lw[6] = {0.1f,0.1f,0.5f,0.5f,1.0f,1.0f};
    const float nn[6] = {16384.f,32768.f,65536.f,131072.f,262144.f,524288.f};
    float L=0.f;
    for (int i=0;i<6;i++) L += lw[i]*((v[2*i] + v[2*i+1])/nn[i]);
    out[0]=L;
  }
}

extern "C" void kernel_launch(void* const* d_in, const int* in_sizes, int n_in,
                              void* d_out, int out_size, void* d_ws, size_t ws_size,
                              hipStream_t stream){
  const float* image  = (const float*)d_in[0];
  const float* w1=(const float*)d_in[2];  const float* b1=(const float*)d_in[3];
  const float* w2=(const float*)d_in[4];  const float* b2=(const float*)d_in[5];
  const float* w3=(const float*)d_in[6];  const float* b3=(const float*)d_in[7];
  const float* w4=(const float*)d_in[8];  const float* b4=(const float*)d_in[9];
  const float* upw=(const float*)d_in[10];const float* upb=(const float*)d_in[11];
  const float* mw=(const float*)d_in[12]; const float* mb=(const float*)d_in[13];
  const float* masks0=(const float*)d_in[14];
  float* out = (float*)d_out;

  char* ws = (char*)d_ws;
  size_t off = 0;
  auto alloc = [&](size_t bytes)->char*{
    char* p = ws + off; off += (bytes + 255) & ~(size_t)255; return p;
  };
  bf16* enc1  = (bf16*)alloc((size_t)8*256*256*16*2);
  bf16* enc2  = (bf16*)alloc((size_t)8*128*128*16*2);
  bf16* enc3  = (bf16*)alloc((size_t)8*64*64*32*2);
  bf16* featA = (bf16*)alloc((size_t)8*256*256*64*2);
  bf16* featB = (bf16*)alloc((size_t)8*256*128*64*2);
  float* mbA  = (float*)alloc((size_t)8*256*128*4);
  float* mbB  = (float*)alloc((size_t)8*128*128*4);
  bf16* packU = (bf16*)alloc((size_t)9*2*4*64*8*2);
  bf16* packM = (bf16*)alloc((size_t)9*2*64*8*2);
  float* acc  = (float*)alloc(12*NSLOT*sizeof(float));

  hipMemsetAsync(acc, 0, 12*NSLOT*sizeof(float), stream);

  repack_up  <<<144,256,0,stream>>>(upw, packU);
  repack_mask<<< 36,256,0,stream>>>(mw,  packM);

  // encoder
  trio_kernel<float,1,16,1,1,256,256><<<8*256*256/256,256,0,stream>>>(image,w1,b1,enc1);
  trio_kernel<bf16,16,16,2,2,256,256><<<8*128*128*2/256,256,0,stream>>>(enc1,w2,b2,enc2);
  trio_kernel<bf16,16,32,8,2,128,128><<<8*64*64*8/256,256,0,stream>>>(enc2,w3,b3,enc3);
  trio_kernel<bf16,32,64,16,2,64,64><<<8*32*32*16/256,256,0,stream>>>(enc3,w4,b4,featA);

  // step 0: (32,32) -> (64,32)
  upconv_dim0<32,32><<<128,256,0,stream>>>(featA,packU,upb,featB);
  maskloss_mfma<0,0,64,32,2><<<128,256,0,stream>>>(featB,packM,mb,image,masks0,mbA,acc);
  // step 1: (64,32) -> (64,64)
  upconv_dim1<64,32><<<256,256,0,stream>>>(featB,packU,upb,featA);
  maskloss_lds<1,1,64,64><<<512,256,0,stream>>>(featA,packM,mb,image,mbA,mbB,acc);
  // step 2: (64,64) -> (128,64)
  upconv_dim0<64,64><<<512,256,0,stream>>>(featA,packU,upb,featB);
  maskloss_lds<2,0,128,64><<<1024,256,0,stream>>>(featB,packM,mb,image,mbB,mbA,acc);
  // step 3: (128,64) -> (128,128)   LDS form: NBq=1 -> 128*8 = 1024 blocks
  upconv_dim1_lds<128,64><<<1024,256,0,stream>>>(featB,packU,upb,featA);
  maskloss_lds<3,1,128,128><<<2048,256,0,stream>>>(featA,packM,mb,image,mbA,mbB,acc);
  // step 4: (128,128) -> (256,128)
  upconv_dim0<128,128><<<2048,256,0,stream>>>(featA,packU,upb,featB);
  maskloss_lds<4,0,256,128><<<4096,256,0,stream>>>(featB,packM,mb,image,mbB,mbA,acc);
  // step 5: (256,128) -> (256,256)  LDS form: NBq=2 -> 2*256*8 = 4096 blocks
  upconv_dim1_lds<256,128><<<4096,256,0,stream>>>(featB,packU,upb,featA);
  maskloss_lds<5,1,256,256><<<8192,256,0,stream>>>(featA,packM,mb,image,mbA,out+1,acc);

  finalize_kernel<<<1,64,0,stream>>>(acc,out);
}

// Round 17
// 463.058 us; speedup vs baseline: 1.1701x; 1.0068x over previous
//
#include <hip/hip_runtime.h>
#include <hip/hip_bf16.h>
#include <math.h>

typedef __hip_bfloat16 bf16;
typedef float f32x4 __attribute__((ext_vector_type(4)));
typedef __bf16 bf16x8 __attribute__((ext_vector_type(8)));

#define DEV __device__ __forceinline__

DEV float to_f(float v){ return v; }
DEV float to_f(bf16 v){ return __bfloat162float(v); }
DEV bf16 f2b(float v){ return __float2bfloat16(v); }
DEV unsigned short b2u(bf16 v){ return __builtin_bit_cast(unsigned short, v); }

DEV float gelu_f(float x){
  float z = 1.5957691216057308f*(x + 0.044715f*x*x*x);
  float e = __expf(-z);
  return x * __builtin_amdgcn_rcpf(1.0f + e);
}

DEV bf16x8 load_frag(const bf16* p, bool ok){
  uint4 u = make_uint4(0u,0u,0u,0u);
  if (ok) u = *(const uint4*)p;
  return __builtin_bit_cast(bf16x8, u);
}

DEV f32x4 mfma16(bf16x8 a, uint4 b, f32x4 c){
  return __builtin_amdgcn_mfma_f32_16x16x32_bf16(a, __builtin_bit_cast(bf16x8, b), c, 0, 0, 0);
}

DEV int swz8(int blk, int n){
  return (blk & 7) * (n >> 3) + (blk >> 3);
}

// async global->LDS DMA, 16 B per lane; lds dest wave-uniform base.
DEV void dma16(const void* g, void* l){
  __builtin_amdgcn_global_load_lds(
      (const __attribute__((address_space(1))) unsigned int*)g,
      (__attribute__((address_space(3))) unsigned int*)l,
      16, 0, 0);
}

#define NSLOT 64

// ---------------- encoder Conv_trio -------------------------------------------
template<typename TIN, int CIN, int COUT, int SUB, int STRIDE, int HI, int WI>
__global__ void trio_kernel(const TIN* __restrict__ in, const float* __restrict__ w,
                            const float* __restrict__ bias, bf16* __restrict__ out){
  constexpr int HO = HI/STRIDE, WO = WI/STRIDE;
  constexpr int CO_PER = COUT/SUB;
  int gtid = blockIdx.x*blockDim.x + threadIdx.x;
  int sub = gtid % SUB;
  int pix = gtid / SUB;
  int b = pix / (HO*WO); int rem = pix % (HO*WO);
  int y = rem / WO, x = rem % WO;

  float acc[CO_PER];
  #pragma unroll
  for (int j=0;j<CO_PER;j++) acc[j]=0.f;

  for (int ky=0;ky<3;ky++){
    int iy = (STRIDE==1) ? (y+ky-1) : (2*y+ky);
    if (iy<0 || iy>=HI) continue;
    for (int kx=0;kx<3;kx++){
      int ix = (STRIDE==1) ? (x+kx-1) : (2*x+kx);
      if (ix<0 || ix>=WI) continue;
      const TIN* ip = in + ((size_t)(b*HI+iy)*WI+ix)*CIN;
      const float* wp = w + ((ky*3+kx)*CIN)*COUT + sub*CO_PER;
      if constexpr (sizeof(TIN)==2 && (CIN%8)==0){
        #pragma unroll
        for (int v=0; v<CIN/8; v++){
          uint4 u = *(const uint4*)((const bf16*)ip + v*8);
          bf16x8 ch = __builtin_bit_cast(bf16x8, u);
          #pragma unroll
          for (int j=0;j<8;j++){
            float a = (float)ch[j];
            const float4* w4 = (const float4*)(wp + (size_t)(v*8+j)*COUT);
            #pragma unroll
            for (int q2=0;q2<CO_PER/4;q2++){
              float4 ww = w4[q2];
              acc[4*q2+0] += a*ww.x; acc[4*q2+1] += a*ww.y;
              acc[4*q2+2] += a*ww.z; acc[4*q2+3] += a*ww.w;
            }
          }
        }
      } else {
        #pragma unroll 4
        for (int ci=0; ci<CIN; ci++){
          float a = to_f(ip[ci]);
          const float4* w4 = (const float4*)(wp + (size_t)ci*COUT);
          #pragma unroll
          for (int j=0;j<CO_PER/4;j++){
            float4 ww = w4[j];
            acc[4*j+0] += a*ww.x; acc[4*j+1] += a*ww.y;
            acc[4*j+2] += a*ww.z; acc[4*j+3] += a*ww.w;
          }
        }
      }
    }
  }

  float s1=0.f, s2=0.f;
  #pragma unroll
  for (int j=0;j<CO_PER;j++){
    acc[j] += bias[sub*CO_PER+j];
    s1 += acc[j]; s2 += acc[j]*acc[j];
  }
  #pragma unroll
  for (int off=1; off<SUB; off<<=1){
    s1 += __shfl_xor(s1,off,64);
    s2 += __shfl_xor(s2,off,64);
  }
  float mu  = s1*(1.0f/COUT);
  float var = s2*(1.0f/COUT) - mu*mu;
  float sc  = rsqrtf(var + 1e-6f);

  bf16* op = out + (size_t)pix*COUT + sub*CO_PER;
  #pragma unroll
  for (int j=0;j<CO_PER;j++) op[j] = f2b(gelu_f((acc[j]-mu)*sc));
}

// ---------------- weight repack -----------------------------------------------
__global__ void repack_up(const float* __restrict__ w, bf16* __restrict__ bp){
  int v = blockIdx.x*256 + threadIdx.x;
  if (v >= 9*2*4*64*8) return;
  int j = v & 7; int lane = (v>>3)&63; int nt = (v>>9)&3; int c = (v>>11)&1; int tap = v>>12;
  int ci = c*32 + (lane>>4)*8 + j;
  int co = (lane&15)*4 + nt;
  bp[v] = f2b(w[(tap*64+ci)*64 + co]);
}

__global__ void repack_mask(const float* __restrict__ w, bf16* __restrict__ bp){
  int v = blockIdx.x*256 + threadIdx.x;
  if (v >= 9*2*64*8) return;
  int j = v & 7; int lane = (v>>3)&63; int c = (v>>9)&1; int tap = v>>10;
  int ci = c*32 + (lane>>4)*8 + j;
  int n = lane & 15;
  bp[v] = (n < 4) ? f2b(w[(tap*64+ci)*4 + n]) : f2b(0.0f);
}

// ------------- conv_transpose, stride-2 along y (DIM=0) -----------------------
template<int HI, int WI>
__global__ void upconv_dim0(const bf16* __restrict__ in, const bf16* __restrict__ bpack,
                            const float* __restrict__ upb, bf16* __restrict__ out){
  constexpr int HO = 2*HI, WO = WI, XT = WI/32;
  int lane = threadIdx.x & 63, wv = threadIdx.x >> 6;
  int wtile = swz8(blockIdx.x, gridDim.x)*4 + wv;
  int m = lane & 15, quad = lane >> 4;

  int x0 = (wtile % XT)*32;
  int o  = (wtile / XT) % HO;
  int b  = wtile / (XT*HO);

  int q = o >> 1;
  int stk[2], stq[2]; int nst;
  if (o & 1){ stk[0]=1; stq[0]=q; nst=1; }
  else {
    nst = 0;
    if (q >= 1){ stk[0]=0; stq[0]=q-1; nst=1; }
    stk[nst]=2; stq[nst]=q; nst++;
  }

  f32x4 acc[2][4];
  #pragma unroll
  for (int t=0;t<2;t++)
    #pragma unroll
    for (int nt=0;nt<4;nt++) acc[t][nt] = (f32x4){0.f,0.f,0.f,0.f};

  const uint4* bp4 = (const uint4*)bpack;

  #pragma unroll 1
  for (int s=0; s<nst; s++){
    int kyt = stk[s];
    const bf16* rowp = in + ((size_t)(b*HI+stq[s])*WI)*64 + quad*8;
    #pragma unroll
    for (int ut=0; ut<3; ut++){
      #pragma unroll
      for (int c=0;c<2;c++){
        int ix0 = x0 + m - 1 + ut;
        int ix1 = ix0 + 16;
        bf16x8 a0 = load_frag(rowp + (size_t)ix0*64 + c*32, ix0>=0 && ix0<WI);
        bf16x8 a1 = load_frag(rowp + (size_t)ix1*64 + c*32, ix1>=0 && ix1<WI);
        #pragma unroll
        for (int nt=0;nt<4;nt++){
          uint4 Bq = bp4[(((kyt*3+ut)*2+c)*4+nt)*64 + lane];
          acc[0][nt] = mfma16(a0, Bq, acc[0][nt]);
          acc[1][nt] = mfma16(a1, Bq, acc[1][nt]);
        }
      }
    }
  }

  float4 bv = *(const float4*)(upb + m*4);
  size_t rowbase = ((size_t)b*HO + o)*WO;
  #pragma unroll
  for (int t=0;t<2;t++){
    #pragma unroll
    for (int r=0;r<4;r++){
      int p = x0 + t*16 + quad*4 + r;
      float g0 = gelu_f(acc[t][0][r] + bv.x);
      float g1 = gelu_f(acc[t][1][r] + bv.y);
      float g2 = gelu_f(acc[t][2][r] + bv.z);
      float g3 = gelu_f(acc[t][3][r] + bv.w);
      unsigned int lo = (unsigned int)b2u(f2b(g0)) | ((unsigned int)b2u(f2b(g1))<<16);
      unsigned int hi = (unsigned int)b2u(f2b(g2)) | ((unsigned int)b2u(f2b(g3))<<16);
      *(uint2*)(out + (rowbase + p)*64 + m*4) = make_uint2(lo,hi);
    }
  }
}

// ------------- conv_transpose dim1, register form — step 1 (WI=32) only -------
template<int HI, int WI>
__global__ void upconv_dim1(const bf16* __restrict__ in, const bf16* __restrict__ bpack,
                            const float* __restrict__ upb, bf16* __restrict__ out){
  constexpr int HO = HI, WO = 2*WI, QT = WI/16;
  int lane = threadIdx.x & 63, wv = threadIdx.x >> 6;
  int wtile = swz8(blockIdx.x, gridDim.x)*4 + wv;
  int m = lane & 15, quad = lane >> 4;

  int q0 = (wtile % QT)*16;
  int y  = (wtile / QT) % HI;
  int b  = wtile / (QT*HI);

  f32x4 ae[4], ao[4];
  #pragma unroll
  for (int nt=0;nt<4;nt++){ ae[nt]=(f32x4){0.f,0.f,0.f,0.f}; ao[nt]=(f32x4){0.f,0.f,0.f,0.f}; }

  const uint4* bp4 = (const uint4*)bpack;

  #pragma unroll 1
  for (int ky=0; ky<3; ky++){
    int iy = y + ky - 1;
    if (iy < 0 || iy >= HI) continue;
    const bf16* rowp = in + ((size_t)(b*HI+iy)*WI)*64 + quad*8;
    #pragma unroll
    for (int c=0;c<2;c++){
      int qa = q0 + m;
      bf16x8 Au = load_frag(rowp + (size_t)qa*64 + c*32, true);
      bf16x8 As = load_frag(rowp + (size_t)(qa-1)*64 + c*32, qa >= 1);
      #pragma unroll
      for (int nt=0;nt<4;nt++){
        uint4 B0 = bp4[(((ky*3+0)*2+c)*4+nt)*64 + lane];
        uint4 B1 = bp4[(((ky*3+1)*2+c)*4+nt)*64 + lane];
        uint4 B2 = bp4[(((ky*3+2)*2+c)*4+nt)*64 + lane];
        ae[nt] = mfma16(As, B0, ae[nt]);
        ae[nt] = mfma16(Au, B2, ae[nt]);
        ao[nt] = mfma16(Au, B1, ao[nt]);
      }
    }
  }

  float4 bv = *(const float4*)(upb + m*4);
  size_t rowbase = ((size_t)b*HO + y)*WO;
  #pragma unroll
  for (int r=0;r<4;r++){
    int qq = q0 + quad*4 + r;
    {
      float g0 = gelu_f(ae[0][r] + bv.x);
      float g1 = gelu_f(ae[1][r] + bv.y);
      float g2 = gelu_f(ae[2][r] + bv.z);
      float g3 = gelu_f(ae[3][r] + bv.w);
      unsigned int lo = (unsigned int)b2u(f2b(g0)) | ((unsigned int)b2u(f2b(g1))<<16);
      unsigned int hi = (unsigned int)b2u(f2b(g2)) | ((unsigned int)b2u(f2b(g3))<<16);
      *(uint2*)(out + (rowbase + 2*qq)*64 + m*4) = make_uint2(lo,hi);
    }
    {
      float g0 = gelu_f(ao[0][r] + bv.x);
      float g1 = gelu_f(ao[1][r] + bv.y);
      float g2 = gelu_f(ao[2][r] + bv.z);
      float g3 = gelu_f(ao[3][r] + bv.w);
      unsigned int lo = (unsigned int)b2u(f2b(g0)) | ((unsigned int)b2u(f2b(g1))<<16);
      unsigned int hi = (unsigned int)b2u(f2b(g2)) | ((unsigned int)b2u(f2b(g3))<<16);
      *(uint2*)(out + (rowbase + 2*qq+1)*64 + m*4) = make_uint2(lo,hi);
    }
  }
}

// ------------- conv_transpose dim1, WAVE-PRIVATE async LDS staging -------------
// Each wave stages its own 17-px window (3 rows x 3 chunks, chunk-aligned at
// qw-8) into a private 9 KB LDS slice -> NO __syncthreads; s_waitcnt vmcnt(0)
// waits only this wave's DMAs. Left halo (q=-1, slot 7) zeroed per-wave.
template<int HI, int WI>
__global__ void upconv_dim1_lds(const bf16* __restrict__ in, const bf16* __restrict__ bpack,
                                const float* __restrict__ upb, bf16* __restrict__ out){
  constexpr int HO = HI, WO = 2*WI, NBq = WI/64;
  __shared__ __align__(16) char smem[4*3*3072];     // [wave][row][24 px * 128 B]
  int tid = threadIdx.x, lane = tid & 63, wv = tid >> 6;
  int bi = swz8(blockIdx.x, gridDim.x);
  int q0 = (bi % NBq)*64;
  int y  = (bi / NBq) % HI;
  int b  = bi / (NBq*HI);
  int m = lane & 15, quad = lane >> 4;
  int qw = q0 + wv*16;                               // wave's first q
  char* my = smem + wv*3*3072;

  bool rok[3];
  #pragma unroll
  for (int r=0;r<3;r++){ int iy=y+r-1; rok[r] = (iy>=0)&&(iy<HI); }

  // stage 3 rows x 3 chunks of 1024 B, window starts at S = qw-8
  #pragma unroll
  for (int r=0;r<3;r++){
    if (!rok[r]) continue;
    int iy = y + r - 1;
    const char* g = (const char*)(in + ((size_t)(b*HI+iy)*WI + qw - 8)*64) + lane*16;
    #pragma unroll
    for (int k=0;k<3;k++)
      dma16(g + k*1024, my + r*3072 + k*1024);
  }
  asm volatile("s_waitcnt vmcnt(0)" ::: "memory");
  if (qw == 0 && lane < 32){
    #pragma unroll
    for (int r=0;r<3;r++)
      ((float*)(my + r*3072 + 7*128))[lane] = 0.f;   // zero q=-1 slot
  }

  f32x4 ae[4], ao[4];
  #pragma unroll
  for (int nt=0;nt<4;nt++){ ae[nt]=(f32x4){0.f,0.f,0.f,0.f}; ao[nt]=(f32x4){0.f,0.f,0.f,0.f}; }

  const uint4* bp4 = (const uint4*)bpack;

  #pragma unroll 1
  for (int ky=0; ky<3; ky++){
    if (!rok[ky]) continue;
    const char* rowl = my + ky*3072;
    #pragma unroll
    for (int c=0;c<2;c++){
      // Au: q = qw+m -> slot m+8 ; As: q = qw+m-1 -> slot m+7
      bf16x8 Au = __builtin_bit_cast(bf16x8, *(const uint4*)(rowl + (size_t)(m+8)*128 + quad*16 + c*64));
      bf16x8 As = __builtin_bit_cast(bf16x8, *(const uint4*)(rowl + (size_t)(m+7)*128 + quad*16 + c*64));
      #pragma unroll
      for (int nt=0;nt<4;nt++){
        uint4 B0 = bp4[(((ky*3+0)*2+c)*4+nt)*64 + lane];
        uint4 B1 = bp4[(((ky*3+1)*2+c)*4+nt)*64 + lane];
        uint4 B2 = bp4[(((ky*3+2)*2+c)*4+nt)*64 + lane];
        ae[nt] = mfma16(As, B0, ae[nt]);
        ae[nt] = mfma16(Au, B2, ae[nt]);
        ao[nt] = mfma16(Au, B1, ao[nt]);
      }
    }
  }

  float4 bv = *(const float4*)(upb + m*4);
  size_t rowbase = ((size_t)b*HO + y)*WO;
  #pragma unroll
  for (int r=0;r<4;r++){
    int qq = qw + quad*4 + r;
    {
      float g0 = gelu_f(ae[0][r] + bv.x);
      float g1 = gelu_f(ae[1][r] + bv.y);
      float g2 = gelu_f(ae[2][r] + bv.z);
      float g3 = gelu_f(ae[3][r] + bv.w);
      unsigned int lo = (unsigned int)b2u(f2b(g0)) | ((unsigned int)b2u(f2b(g1))<<16);
      unsigned int hi = (unsigned int)b2u(f2b(g2)) | ((unsigned int)b2u(f2b(g3))<<16);
      *(uint2*)(out + (rowbase + 2*qq)*64 + m*4) = make_uint2(lo,hi);
    }
    {
      float g0 = gelu_f(ao[0][r] + bv.x);
      float g1 = gelu_f(ao[1][r] + bv.y);
      float g2 = gelu_f(ao[2][r] + bv.z);
      float g3 = gelu_f(ao[3][r] + bv.w);
      unsigned int lo = (unsigned int)b2u(f2b(g0)) | ((unsigned int)b2u(f2b(g1))<<16);
      unsigned int hi = (unsigned int)b2u(f2b(g2)) | ((unsigned int)b2u(f2b(g3))<<16);
      *(uint2*)(out + (rowbase + 2*qq+1)*64 + m*4) = make_uint2(lo,hi);
    }
  }
}

// ---------------- maskloss, register form — step 0 only ------------------------
template<int STEP, int DIM, int HH, int WW, int TILES>
__global__ void maskloss_mfma(const bf16* __restrict__ feat, const bf16* __restrict__ mpack,
                              const float* __restrict__ mb, const float* __restrict__ img,
                              const float* __restrict__ masks_in, float* __restrict__ masks_out,
                              float* __restrict__ accbuf){
  __shared__ float llog[4][64][4];
  __shared__ float red[4][2];
  int lane = threadIdx.x & 63;
  int wv   = threadIdx.x >> 6;
  int wtile = swz8(blockIdx.x, gridDim.x)*4 + wv;
  int m = lane & 15, quad = lane >> 4;

  constexpr int TPR = WW/(16*TILES);
  int x0 = (wtile % TPR)*(16*TILES);
  int y  = (wtile / TPR) % HH;
  int b  = wtile / (TPR*HH);

  const uint4* bp4 = (const uint4*)mpack;

  #pragma unroll 1
  for (int t=0; t<TILES; t++){
    f32x4 acc4 = (f32x4){0.f,0.f,0.f,0.f};
    #pragma unroll
    for (int c=0;c<2;c++){
      bf16x8 afr[9];
      #pragma unroll
      for (int ky=0; ky<3; ky++){
        int iy = y + ky - 1;
        bool rowok = (iy >= 0) && (iy < HH);
        const bf16* rowp = feat + ((size_t)(b*HH+iy)*WW)*64 + quad*8 + c*32;
        #pragma unroll
        for (int kx=0; kx<3; kx++){
          int ix = x0 + t*16 + m + kx - 1;
          bool ok = rowok && (ix >= 0) && (ix < WW);
          afr[ky*3+kx] = load_frag(rowp + (size_t)ix*64, ok);
        }
      }
      #pragma unroll
      for (int tap=0; tap<9; tap++){
        uint4 bb = bp4[(tap*2+c)*64 + lane];
        acc4 = mfma16(afr[tap], bb, acc4);
      }
    }
    if (m < 4){
      #pragma unroll
      for (int r=0;r<4;r++) llog[wv][t*16 + quad*4 + r][m] = acc4[r] + mb[m];
    }
  }
  __syncthreads();

  float ent = 0.f, mse = 0.f;
  if (lane < 16*TILES){
    int p = lane; int xx = x0 + p;
    float l0 = llog[wv][p][0], l1 = llog[wv][p][1];
    float l2 = llog[wv][p][2], l3 = llog[wv][p][3];
    float mx = fmaxf(fmaxf(l0,l1), fmaxf(l2,l3));
    float e0=__expf(l0-mx), e1=__expf(l1-mx), e2=__expf(l2-mx), e3=__expf(l3-mx);
    float inv = __builtin_amdgcn_rcpf(e0+e1+e2+e3);
    float p0=e0*inv, p1=e1*inv, p2=e2*inv, p3=e3*inv;
    float sval = p1 + 2.f*p2 + 3.f*p3;

    constexpr int HM = (DIM==0)? HH/2 : HH;
    constexpr int WM = (DIM==0)? WW : WW/2;
    int my = (DIM==0)? (y>>1) : y;
    int mxi = (DIM==1)? (xx>>1) : xx;
    float mv = masks_in[((size_t)b*HM + my)*WM + mxi];
    masks_out[((size_t)b*HH + y)*WW + xx] = mv + 0.25f*sval;

    ent = -(p0*__logf(p0+1e-8f) + p1*__logf(p1+1e-8f) +
            p2*__logf(p2+1e-8f) + p3*__logf(p3+1e-8f));

    constexpr int FH = 256/HH, FW = 256/WW;
    float isum = 0.f;
    const float* ib = img + ((size_t)b*256 + y*FH)*256 + xx*FW;
    #pragma unroll
    for (int dy=0; dy<FH; dy++)
      #pragma unroll
      for (int dx=0; dx<FW; dx++) isum += ib[dy*256+dx];
    float img_ds = isum * (1.0f/(FH*FW));
    float d = sval*(1.0f/3.0f) - img_ds;
    mse = d*d;
  }

  #pragma unroll
  for (int off=1; off<64; off<<=1){
    ent += __shfl_xor(ent, off, 64);
    mse += __shfl_xor(mse, off, 64);
  }
  if (lane == 0){ red[wv][0] = ent; red[wv][1] = mse; }
  __syncthreads();
  if (threadIdx.x == 0){
    float e  = red[0][0] + red[1][0] + red[2][0] + red[3][0];
    float ms = red[0][1] + red[1][1] + red[2][1] + red[3][1];
    int slot = blockIdx.x & (NSLOT-1);
    atomicAdd(accbuf + (2*STEP  )*NSLOT + slot, e);
    atomicAdd(accbuf + (2*STEP+1)*NSLOT + slot, ms);
  }
}

// ---------------- maskloss via async LDS staging (WW >= 64) --------------------
template<int STEP, int DIM, int HH, int WW>
__global__ void maskloss_lds(const bf16* __restrict__ feat, const bf16* __restrict__ mpack,
                             const float* __restrict__ mb, const float* __restrict__ img,
                             const float* __restrict__ masks_in, float* __restrict__ masks_out,
                             float* __restrict__ accbuf){
  constexpr int NBrow = WW/64;
  constexpr int PITCH = 9216;                // 72 px * 128 B
  __shared__ __align__(16) char smem[3*PITCH];
  __shared__ float llog[4][16][4];
  __shared__ float red[4][2];
  int tid = threadIdx.x;
  int lane = tid & 63, wv = tid >> 6;
  int bi = swz8(blockIdx.x, gridDim.x);
  int x0 = (bi % NBrow)*64;
  int y  = (bi / NBrow) % HH;
  int b  = bi / (NBrow*HH);
  int m = lane & 15, quad = lane >> 4;

  bool rok[3];
  #pragma unroll
  for (int r=0;r<3;r++){ int iy=y+r-1; rok[r] = (iy>=0)&&(iy<HH); }

  for (int k = wv; k < 27; k += 4){
    int r = k/9, coff = (k%9)*1024;
    if (!rok[r]) continue;
    int iy = y + r - 1;
    const char* g = (const char*)(feat + ((size_t)(b*HH+iy)*WW + x0 - 1)*64)
                    + coff + lane*16;
    dma16(g, smem + r*PITCH + coff);
  }
  asm volatile("s_waitcnt vmcnt(0)" ::: "memory");
  __syncthreads();
  if (x0 == 0 && tid < 96)
    ((float*)(smem + (tid>>5)*PITCH))[tid & 31] = 0.f;
  if (x0 + 64 == WW && tid >= 128 && tid < 224){
    int t = tid - 128;
    ((float*)(smem + (t>>5)*PITCH + 65*128))[t & 31] = 0.f;
  }
  __syncthreads();

  const uint4* bp4 = (const uint4*)mpack;
  f32x4 accA = (f32x4){0.f,0.f,0.f,0.f};
  f32x4 accB = (f32x4){0.f,0.f,0.f,0.f};
  #pragma unroll 1
  for (int ky=0; ky<3; ky++){
    if (!rok[ky]) continue;
    const char* rowl = smem + ky*PITCH;
    #pragma unroll
    for (int kx=0; kx<3; kx++){
      int lp = wv*16 + m + kx;
      const char* pl = rowl + lp*128 + quad*16;
      bf16x8 a0 = __builtin_bit_cast(bf16x8, *(const uint4*)(pl));
      bf16x8 a1 = __builtin_bit_cast(bf16x8, *(const uint4*)(pl + 64));
      uint4 b0 = bp4[((ky*3+kx)*2+0)*64 + lane];
      uint4 b1 = bp4[((ky*3+kx)*2+1)*64 + lane];
      accA = mfma16(a0, b0, accA);
      accB = mfma16(a1, b1, accB);
    }
  }

  if (m < 4){
    #pragma unroll
    for (int r=0;r<4;r++) llog[wv][quad*4+r][m] = accA[r] + accB[r] + mb[m];
  }
  __syncthreads();

  float ent = 0.f, mse = 0.f;
  if (lane < 16){
    int p = lane; int xx = x0 + wv*16 + p;
    float l0 = llog[wv][p][0], l1 = llog[wv][p][1];
    float l2 = llog[wv][p][2], l3 = llog[wv][p][3];
    float mx = fmaxf(fmaxf(l0,l1), fmaxf(l2,l3));
    float e0=__expf(l0-mx), e1=__expf(l1-mx), e2=__expf(l2-mx), e3=__expf(l3-mx);
    float inv = __builtin_amdgcn_rcpf(e0+e1+e2+e3);
    float p0=e0*inv, p1=e1*inv, p2=e2*inv, p3=e3*inv;
    float sval = p1 + 2.f*p2 + 3.f*p3;

    constexpr int HM = (DIM==0)? HH/2 : HH;
    constexpr int WM = (DIM==0)? WW : WW/2;
    int my = (DIM==0)? (y>>1) : y;
    int mxi = (DIM==1)? (xx>>1) : xx;
    float mv = masks_in[((size_t)b*HM + my)*WM + mxi];
    masks_out[((size_t)b*HH + y)*WW + xx] = mv + 0.25f*sval;

    ent = -(p0*__logf(p0+1e-8f) + p1*__logf(p1+1e-8f) +
            p2*__logf(p2+1e-8f) + p3*__logf(p3+1e-8f));

    constexpr int FH = 256/HH, FW = 256/WW;
    float isum = 0.f;
    const float* ib = img + ((size_t)b*256 + y*FH)*256 + xx*FW;
    #pragma unroll
    for (int dy=0; dy<FH; dy++)
      #pragma unroll
      for (int dx=0; dx<FW; dx++) isum += ib[dy*256+dx];
    float img_ds = isum * (1.0f/(FH*FW));
    float d = sval*(1.0f/3.0f) - img_ds;
    mse = d*d;
  }

  #pragma unroll
  for (int off=1; off<64; off<<=1){
    ent += __shfl_xor(ent, off, 64);
    mse += __shfl_xor(mse, off, 64);
  }
  if (lane == 0){ red[wv][0] = ent; red[wv][1] = mse; }
  __syncthreads();
  if (threadIdx.x == 0){
    float e  = red[0][0] + red[1][0] + red[2][0] + red[3][0];
    float ms = red[0][1] + red[1][1] + red[2][1] + red[3][1];
    int slot = blockIdx.x & (NSLOT-1);
    atomicAdd(accbuf + (2*STEP  )*NSLOT + slot, e);
    atomicAdd(accbuf + (2*STEP+1)*NSLOT + slot, ms);
  }
}

__global__ void finalize_kernel(const float* __restrict__ acc, float* __restrict__ out){
  int lane = threadIdx.x & 63;
  float v[12];
  #pragma unroll
  for (int i=0;i<12;i++){
    float x = acc[i*NSLOT + lane];
    #pragma unroll
    for (int off=1; off<64; off<<=1) x += __shfl_xor(x, off, 64);
    v[i] = x;
  }
  if (lane == 0){
    const float lw[6] = {0.1f,0.1f,0.5f,0.5f,1.0f,1.0f};
    const float nn[6] = {16384.f,32768.f,65536.f,131072.f,262144.f,524288.f};
    float L=0.f;
    for (int i=0;i<6;i++) L += lw[i]*((v[2*i] + v[2*i+1])/nn[i]);
    out[0]=L;
  }
}

extern "C" void kernel_launch(void* const* d_in, const int* in_sizes, int n_in,
                              void* d_out, int out_size, void* d_ws, size_t ws_size,
                              hipStream_t stream){
  const float* image  = (const float*)d_in[0];
  const float* w1=(const float*)d_in[2];  const float* b1=(const float*)d_in[3];
  const float* w2=(const float*)d_in[4];  const float* b2=(const float*)d_in[5];
  const float* w3=(const float*)d_in[6];  const float* b3=(const float*)d_in[7];
  const float* w4=(const float*)d_in[8];  const float* b4=(const float*)d_in[9];
  const float* upw=(const float*)d_in[10];const float* upb=(const float*)d_in[11];
  const float* mw=(const float*)d_in[12]; const float* mb=(const float*)d_in[13];
  const float* masks0=(const float*)d_in[14];
  float* out = (float*)d_out;

  char* ws = (char*)d_ws;
  size_t off = 0;
  auto alloc = [&](size_t bytes)->char*{
    char* p = ws + off; off += (bytes + 255) & ~(size_t)255; return p;
  };
  bf16* enc1  = (bf16*)alloc((size_t)8*256*256*16*2);
  bf16* enc2  = (bf16*)alloc((size_t)8*128*128*16*2);
  bf16* enc3  = (bf16*)alloc((size_t)8*64*64*32*2);
  bf16* featA = (bf16*)alloc((size_t)8*256*256*64*2);
  bf16* featB = (bf16*)alloc((size_t)8*256*128*64*2);
  float* mbA  = (float*)alloc((size_t)8*256*128*4);
  float* mbB  = (float*)alloc((size_t)8*128*128*4);
  bf16* packU = (bf16*)alloc((size_t)9*2*4*64*8*2);
  bf16* packM = (bf16*)alloc((size_t)9*2*64*8*2);
  float* acc  = (float*)alloc(12*NSLOT*sizeof(float));

  hipMemsetAsync(acc, 0, 12*NSLOT*sizeof(float), stream);

  repack_up  <<<144,256,0,stream>>>(upw, packU);
  repack_mask<<< 36,256,0,stream>>>(mw,  packM);

  // encoder
  trio_kernel<float,1,16,1,1,256,256><<<8*256*256/256,256,0,stream>>>(image,w1,b1,enc1);
  trio_kernel<bf16,16,16,2,2,256,256><<<8*128*128*2/256,256,0,stream>>>(enc1,w2,b2,enc2);
  trio_kernel<bf16,16,32,8,2,128,128><<<8*64*64*8/256,256,0,stream>>>(enc2,w3,b3,enc3);
  trio_kernel<bf16,32,64,16,2,64,64><<<8*32*32*16/256,256,0,stream>>>(enc3,w4,b4,featA);

  // step 0: (32,32) -> (64,32)
  upconv_dim0<32,32><<<128,256,0,stream>>>(featA,packU,upb,featB);
  maskloss_mfma<0,0,64,32,2><<<128,256,0,stream>>>(featB,packM,mb,image,masks0,mbA,acc);
  // step 1: (64,32) -> (64,64)
  upconv_dim1<64,32><<<256,256,0,stream>>>(featB,packU,upb,featA);
  maskloss_lds<1,1,64,64><<<512,256,0,stream>>>(featA,packM,mb,image,mbA,mbB,acc);
  // step 2: (64,64) -> (128,64)
  upconv_dim0<64,64><<<512,256,0,stream>>>(featA,packU,upb,featB);
  maskloss_lds<2,0,128,64><<<1024,256,0,stream>>>(featB,packM,mb,image,mbB,mbA,acc);
  // step 3: (128,64) -> (128,128)
  upconv_dim1_lds<128,64><<<1024,256,0,stream>>>(featB,packU,upb,featA);
  maskloss_lds<3,1,128,128><<<2048,256,0,stream>>>(featA,packM,mb,image,mbA,mbB,acc);
  // step 4: (128,128) -> (256,128)
  upconv_dim0<128,128><<<2048,256,0,stream>>>(featA,packU,upb,featB);
  maskloss_lds<4,0,256,128><<<4096,256,0,stream>>>(featB,packM,mb,image,mbB,mbA,acc);
  // step 5: (256,128) -> (256,256)
  upconv_dim1_lds<256,128><<<4096,256,0,stream>>>(featB,packU,upb,featA);
  maskloss_lds<5,1,256,256><<<8192,256,0,stream>>>(featA,packM,mb,image,mbA,out+1,acc);

  finalize_kernel<<<1,64,0,stream>>>(acc,out);
}